// Round 10
// baseline (2406.180 us; speedup 1.0000x reference)
//
#include <hip/hip_runtime.h>
#include <math.h>

#define N_NODES 200000
#define N_EDGES 3200000
#define M_SEL   100000
#define NEX     32
#define NT      11
#define CH      32
#define HID     1024
#define NL      8
#define BN_EPS  1e-5f

#define BSHIFT  9
#define BSIZE   512
#define KB      391
#define PAYMASK 0x3FFFF
#define NWIN    1563                     // ceil(N/128) windows of 128 nodes

// bf16 helpers (RNE)
__device__ __forceinline__ unsigned bf16_bits(float f) {
  unsigned u = __float_as_uint(f);
  return (u + 0x7fffu + ((u >> 16) & 1u)) >> 16;
}
__device__ __forceinline__ unsigned pack_bf2(float lo, float hi) {
  return bf16_bits(lo) | (bf16_bits(hi) << 16);
}
#define BF_LO(u) __uint_as_float((u) << 16)
#define BF_HI(u) __uint_as_float((u) & 0xffff0000u)

// ---------------------------------------------------------------------------
// CSR build (radix-partition, R5 — measured good)
// ---------------------------------------------------------------------------
__global__ void __launch_bounds__(256) bin_count_kernel(
    const int* __restrict__ src, const int* __restrict__ dst,
    int* __restrict__ bcnt_in, int* __restrict__ bcnt_out) {
  __shared__ int h_in[KB], h_out[KB];
  int tid = threadIdx.x;
  for (int i = tid; i < KB; i += 256) { h_in[i] = 0; h_out[i] = 0; }
  __syncthreads();
  for (int e = blockIdx.x * 256 + tid; e < N_EDGES; e += gridDim.x * 256) {
    atomicAdd(&h_in[dst[e] >> BSHIFT], 1);
    atomicAdd(&h_out[src[e] >> BSHIFT], 1);
  }
  __syncthreads();
  for (int b = tid; b < KB; b += 256) {
    if (h_in[b])  atomicAdd(&bcnt_in[b], h_in[b]);
    if (h_out[b]) atomicAdd(&bcnt_out[b], h_out[b]);
  }
}

__global__ void __launch_bounds__(256) bucket_scan_kernel(
    const int* __restrict__ bcnt_in, int* __restrict__ boff_in, int* __restrict__ gcur_in,
    const int* __restrict__ bcnt_out, int* __restrict__ boff_out, int* __restrict__ gcur_out) {
  __shared__ int s[512];
  __shared__ int wtot[4];
  int tid = threadIdx.x;
  int lane = tid & 63, wid = tid >> 6;
  for (int dir = 0; dir < 2; dir++) {
    const int* bcnt = dir ? bcnt_out : bcnt_in;
    int* boff = dir ? boff_out : boff_in;
    int* gcur = dir ? gcur_out : gcur_in;
    int i0 = 2 * tid, i1 = 2 * tid + 1;
    int a0 = (i0 < KB) ? bcnt[i0] : 0;
    int a1 = (i1 < KB) ? bcnt[i1] : 0;
    int pair = a0 + a1;
    int incl = pair;
#pragma unroll
    for (int o = 1; o < 64; o <<= 1) { int t = __shfl_up(incl, o); if (lane >= o) incl += t; }
    if (lane == 63) wtot[wid] = incl;
    __syncthreads();
    if (tid == 0) { int r = 0; for (int w = 0; w < 4; w++) { int v = wtot[w]; wtot[w] = r; r += v; } }
    __syncthreads();
    int exclp = incl - pair + wtot[wid];
    s[i0] = exclp;
    s[i1] = exclp + a0;
    __syncthreads();
    for (int b = tid; b < KB; b += 256) { boff[b] = s[b]; gcur[b] = s[b]; }
    if (i0 == KB - 1) boff[KB] = s[i0] + a0;
    if (i1 == KB - 1) boff[KB] = s[i1] + a1;
    __syncthreads();
  }
}

__global__ void __launch_bounds__(256) stage_kernel(
    const int* __restrict__ src, const int* __restrict__ dst,
    int* __restrict__ gcur_in, unsigned* __restrict__ staging_in,
    int* __restrict__ gcur_out, unsigned* __restrict__ staging_out) {
  __shared__ int cnt[KB], cur[KB];
  int tid = threadIdx.x;
  int dir = blockIdx.y;
  const int* key = dir ? src : dst;
  const int* pay = dir ? dst : src;
  int* gcur = dir ? gcur_out : gcur_in;
  unsigned* staging = dir ? staging_out : staging_in;
  for (int i = tid; i < KB; i += 256) cnt[i] = 0;
  __syncthreads();
  int e0 = blockIdx.x * 4096;
#pragma unroll
  for (int j = 0; j < 16; j++) {
    int e = e0 + j * 256 + tid;
    if (e < N_EDGES) atomicAdd(&cnt[key[e] >> BSHIFT], 1);
  }
  __syncthreads();
  for (int b = tid; b < KB; b += 256) {
    int c = cnt[b];
    cur[b] = c ? atomicAdd(&gcur[b], c) : 0;
  }
  __syncthreads();
#pragma unroll
  for (int j = 0; j < 16; j++) {
    int e = e0 + j * 256 + tid;
    if (e < N_EDGES) {
      int k = key[e];
      int b = k >> BSHIFT;
      int p = atomicAdd(&cur[b], 1);
      staging[p] = ((unsigned)(k & (BSIZE - 1)) << 18) | (unsigned)pay[e];
    }
  }
}

__global__ void __launch_bounds__(256) build_kernel(
    const unsigned* __restrict__ staging_in, const int* __restrict__ boff_in,
    int* __restrict__ off_in, int* __restrict__ csr_in,
    const unsigned* __restrict__ staging_out, const int* __restrict__ boff_out,
    int* __restrict__ off_out, int* __restrict__ csr_out) {
  __shared__ int cnt[BSIZE];
  __shared__ int wtot[4];
  int tid = threadIdx.x;
  int b = blockIdx.x;
  int dir = blockIdx.y;
  const unsigned* staging = dir ? staging_out : staging_in;
  const int* boff = dir ? boff_out : boff_in;
  int* off = dir ? off_out : off_in;
  int* csr = dir ? csr_out : csr_in;
  int ebase = boff[b], eend = boff[b + 1];
  int node_base = b << BSHIFT;
  int nnodes = min(BSIZE, N_NODES - node_base);
  cnt[2 * tid] = 0; cnt[2 * tid + 1] = 0;
  __syncthreads();
  for (int e = ebase + tid; e < eend; e += 256)
    atomicAdd(&cnt[staging[e] >> 18], 1);
  __syncthreads();
  int i0 = 2 * tid, i1 = 2 * tid + 1;
  int a0 = cnt[i0], a1 = cnt[i1];
  int pair = a0 + a1;
  int lane = tid & 63, wid = tid >> 6;
  int incl = pair;
#pragma unroll
  for (int o = 1; o < 64; o <<= 1) { int t = __shfl_up(incl, o); if (lane >= o) incl += t; }
  if (lane == 63) wtot[wid] = incl;
  __syncthreads();
  if (tid == 0) { int r = 0; for (int w = 0; w < 4; w++) { int v = wtot[w]; wtot[w] = r; r += v; } }
  __syncthreads();
  int exclp = incl - pair + wtot[wid];
  cnt[i0] = exclp;
  cnt[i1] = exclp + a0;
  __syncthreads();
  for (int i = tid; i < nnodes; i += 256) off[node_base + i] = ebase + cnt[i];
  if (b == KB - 1 && tid == 0) off[N_NODES] = boff[KB];
  __syncthreads();
  for (int e = ebase + tid; e < eend; e += 256) {
    unsigned rec = staging[e];
    int p = atomicAdd(&cnt[rec >> 18], 1);
    csr[ebase + p] = (int)(rec & PAYMASK);
  }
}

// ---------------------------------------------------------------------------
// Window degree-sort: one 128-thread block per (128-node window, direction).
// Bitonic sort keys = (min(deg,8191)<<18)|node. Produces perm (slot -> node,
// -1 for pad slots). Sorting stays within the window so agg block reads/
// writes remain inside an 8 KB region (no scatter-write amplification).
// ---------------------------------------------------------------------------
__global__ void __launch_bounds__(128) wsort_kernel(
    const int* __restrict__ off_in, int* __restrict__ perm_in,
    const int* __restrict__ off_out, int* __restrict__ perm_out) {
  __shared__ int keys[128];
  int t = threadIdx.x;
  int dir = blockIdx.y;
  const int* off = dir ? off_out : off_in;
  int* perm = dir ? perm_out : perm_in;
  int node = blockIdx.x * 128 + t;
  int key = 0x7FFFFFFF;
  if (node < N_NODES) {
    int d = off[node + 1] - off[node];
    if (d > 8191) d = 8191;
    key = (d << 18) | node;
  }
  keys[t] = key;
  __syncthreads();
  for (int k = 2; k <= 128; k <<= 1) {
    for (int j = k >> 1; j > 0; j >>= 1) {
      int ixj = t ^ j;
      if (ixj > t) {
        int a = keys[t], b = keys[ixj];
        bool asc = ((t & k) == 0);
        if ((a > b) == asc) { keys[t] = b; keys[ixj] = a; }
      }
      __syncthreads();
    }
  }
  int kk = keys[t];
  perm[blockIdx.x * 128 + t] = (kk == 0x7FFFFFFF) ? -1 : (kk & PAYMASK);
}

// ---------------------------------------------------------------------------
// Pack 32 fp32 acc channels into split bf16 arrays (16 ch each, 32 B rows)
// ---------------------------------------------------------------------------
__device__ __forceinline__ void store_split(unsigned short* y_out,
                                            unsigned short* y_back,
                                            int i, const float* acc) {
  uint4 t0, t1;
  t0.x = pack_bf2(acc[0], acc[1]);   t0.y = pack_bf2(acc[2], acc[3]);
  t0.z = pack_bf2(acc[4], acc[5]);   t0.w = pack_bf2(acc[6], acc[7]);
  t1.x = pack_bf2(acc[8], acc[9]);   t1.y = pack_bf2(acc[10], acc[11]);
  t1.z = pack_bf2(acc[12], acc[13]); t1.w = pack_bf2(acc[14], acc[15]);
  uint4* po = (uint4*)(y_out + (size_t)i * 16);
  po[0] = t0; po[1] = t1;
  t0.x = pack_bf2(acc[16], acc[17]); t0.y = pack_bf2(acc[18], acc[19]);
  t0.z = pack_bf2(acc[20], acc[21]); t0.w = pack_bf2(acc[22], acc[23]);
  t1.x = pack_bf2(acc[24], acc[25]); t1.y = pack_bf2(acc[26], acc[27]);
  t1.z = pack_bf2(acc[28], acc[29]); t1.w = pack_bf2(acc[30], acc[31]);
  uint4* pb = (uint4*)(y_back + (size_t)i * 16);
  pb[0] = t0; pb[1] = t1;
}

// ---------------------------------------------------------------------------
// A0: x0 = emb[nodes]; y = x0 @ [w0_out | w0_back]
// ---------------------------------------------------------------------------
__global__ void __launch_bounds__(256) emb_mm_kernel(
    const int* __restrict__ nodes, const float* __restrict__ emb,
    const float* __restrict__ w_out, const float* __restrict__ w_back,
    unsigned short* __restrict__ y_out, unsigned short* __restrict__ y_back) {
  __shared__ float W[CH][CH];
  __shared__ float Esh[NT * CH];
  int tid = threadIdx.x;
  for (int t = tid; t < CH * CH; t += blockDim.x) {
    int k = t >> 5, j = t & 31;
    W[k][j] = (j < 16) ? w_out[k * 16 + j] : w_back[k * 16 + j - 16];
  }
  for (int t = tid; t < NT * CH; t += blockDim.x) Esh[t] = emb[t];
  __syncthreads();
  int i = blockIdx.x * blockDim.x + tid;
  if (i >= N_NODES) return;
  int tn = nodes[i];
  float v[CH];
#pragma unroll
  for (int k = 0; k < CH; k++) v[k] = Esh[tn * CH + k];
  float acc[CH];
#pragma unroll
  for (int j = 0; j < CH; j++) acc[j] = 0.f;
#pragma unroll
  for (int k = 0; k < CH; k++) {
    float vk = v[k];
#pragma unroll
    for (int j = 0; j < CH; j++) acc[j] += vk * W[k][j];
  }
  store_split(y_out, y_back, i, acc);
}

// ---------------------------------------------------------------------------
// A: y = relu(bn(x)) @ [w_out | w_back]
// ---------------------------------------------------------------------------
__global__ void __launch_bounds__(256) bn_relu_mm_kernel(
    const float* __restrict__ xin, const float* __restrict__ stats,
    const float* __restrict__ gamma, const float* __restrict__ beta,
    const float* __restrict__ w_out, const float* __restrict__ w_back,
    unsigned short* __restrict__ y_out, unsigned short* __restrict__ y_back) {
  __shared__ float W[CH][CH];
  __shared__ float sc[CH], sh[CH];
  int tid = threadIdx.x;
  for (int t = tid; t < CH * CH; t += blockDim.x) {
    int k = t >> 5, j = t & 31;
    W[k][j] = (j < 16) ? w_out[k * 16 + j] : w_back[k * 16 + j - 16];
  }
  if (tid < CH) {
    float m  = stats[tid] * (1.0f / N_NODES);
    float s2 = stats[CH + tid] * (1.0f / N_NODES);
    float var = s2 - m * m;
    float scale = gamma[tid] * rsqrtf(var + BN_EPS);
    sc[tid] = scale;
    sh[tid] = beta[tid] - m * scale;
  }
  __syncthreads();
  int i = blockIdx.x * blockDim.x + tid;
  if (i >= N_NODES) return;
  const float4* xp = (const float4*)(xin + (size_t)i * CH);
  float v[CH];
#pragma unroll
  for (int q = 0; q < 8; q++) {
    float4 t = xp[q];
    v[4 * q + 0] = fmaxf(t.x * sc[4 * q + 0] + sh[4 * q + 0], 0.f);
    v[4 * q + 1] = fmaxf(t.y * sc[4 * q + 1] + sh[4 * q + 1], 0.f);
    v[4 * q + 2] = fmaxf(t.z * sc[4 * q + 2] + sh[4 * q + 2], 0.f);
    v[4 * q + 3] = fmaxf(t.w * sc[4 * q + 3] + sh[4 * q + 3], 0.f);
  }
  float acc[CH];
#pragma unroll
  for (int j = 0; j < CH; j++) acc[j] = 0.f;
#pragma unroll
  for (int k = 0; k < CH; k++) {
    float vk = v[k];
#pragma unroll
    for (int j = 0; j < CH; j++) acc[j] += vk * W[k][j];
  }
  store_split(y_out, y_back, i, acc);
}

// ---------------------------------------------------------------------------
// B: node-parallel gather aggregation, degree-sorted within 128-node windows
// (perm). 2 lanes/node, uint4 loads, x8 unroll. Grid (NWIN, 2); block b
// handles window b -> reads/writes confined to that window's region.
// ---------------------------------------------------------------------------
__global__ void __launch_bounds__(256) agg_dir_kernel(
    const unsigned short* __restrict__ y_out, const unsigned short* __restrict__ y_back,
    const float* __restrict__ xres, float* __restrict__ out,
    const int* __restrict__ off_in, const int* __restrict__ csr_in,
    const int* __restrict__ off_out, const int* __restrict__ csr_out,
    const int* __restrict__ perm_in, const int* __restrict__ perm_out,
    float* __restrict__ stats) {
  __shared__ float ssum[CH], sssq[CH];
  int tid = threadIdx.x;
  if (tid < CH) { ssum[tid] = 0.f; sssq[tid] = 0.f; }
  __syncthreads();
  int dir = blockIdx.y;
  const unsigned short* y = dir ? y_back : y_out;
  const int* off = dir ? off_out : off_in;
  const int* csr = dir ? csr_out : csr_in;
  const int* perm = dir ? perm_out : perm_in;
  int chanbase = dir * 16;
  int slot = blockIdx.x * 128 + (tid >> 1);
  int i = perm[slot];
  bool valid = i >= 0;
  int q = tid & 1;          // which 16 B half of the 32 B row
  int lo = 0, hi = 0;
  if (valid) { lo = off[i]; hi = off[i + 1]; }
  int q8 = q * 8;
  float a0 = 0.f, a1 = 0.f, a2 = 0.f, a3 = 0.f;
  float a4 = 0.f, a5 = 0.f, a6 = 0.f, a7 = 0.f;
  int e = lo;
  for (; e + 8 <= hi; e += 8) {
    int n0 = csr[e + 0], n1 = csr[e + 1], n2 = csr[e + 2], n3 = csr[e + 3];
    int n4 = csr[e + 4], n5 = csr[e + 5], n6 = csr[e + 6], n7 = csr[e + 7];
    uint4 p0 = *(const uint4*)(y + (size_t)n0 * 16 + q8);
    uint4 p1 = *(const uint4*)(y + (size_t)n1 * 16 + q8);
    uint4 p2 = *(const uint4*)(y + (size_t)n2 * 16 + q8);
    uint4 p3 = *(const uint4*)(y + (size_t)n3 * 16 + q8);
    uint4 p4 = *(const uint4*)(y + (size_t)n4 * 16 + q8);
    uint4 p5 = *(const uint4*)(y + (size_t)n5 * 16 + q8);
    uint4 p6 = *(const uint4*)(y + (size_t)n6 * 16 + q8);
    uint4 p7 = *(const uint4*)(y + (size_t)n7 * 16 + q8);
    a0 += BF_LO(p0.x) + BF_LO(p1.x) + BF_LO(p2.x) + BF_LO(p3.x)
        + BF_LO(p4.x) + BF_LO(p5.x) + BF_LO(p6.x) + BF_LO(p7.x);
    a1 += BF_HI(p0.x) + BF_HI(p1.x) + BF_HI(p2.x) + BF_HI(p3.x)
        + BF_HI(p4.x) + BF_HI(p5.x) + BF_HI(p6.x) + BF_HI(p7.x);
    a2 += BF_LO(p0.y) + BF_LO(p1.y) + BF_LO(p2.y) + BF_LO(p3.y)
        + BF_LO(p4.y) + BF_LO(p5.y) + BF_LO(p6.y) + BF_LO(p7.y);
    a3 += BF_HI(p0.y) + BF_HI(p1.y) + BF_HI(p2.y) + BF_HI(p3.y)
        + BF_HI(p4.y) + BF_HI(p5.y) + BF_HI(p6.y) + BF_HI(p7.y);
    a4 += BF_LO(p0.z) + BF_LO(p1.z) + BF_LO(p2.z) + BF_LO(p3.z)
        + BF_LO(p4.z) + BF_LO(p5.z) + BF_LO(p6.z) + BF_LO(p7.z);
    a5 += BF_HI(p0.z) + BF_HI(p1.z) + BF_HI(p2.z) + BF_HI(p3.z)
        + BF_HI(p4.z) + BF_HI(p5.z) + BF_HI(p6.z) + BF_HI(p7.z);
    a6 += BF_LO(p0.w) + BF_LO(p1.w) + BF_LO(p2.w) + BF_LO(p3.w)
        + BF_LO(p4.w) + BF_LO(p5.w) + BF_LO(p6.w) + BF_LO(p7.w);
    a7 += BF_HI(p0.w) + BF_HI(p1.w) + BF_HI(p2.w) + BF_HI(p3.w)
        + BF_HI(p4.w) + BF_HI(p5.w) + BF_HI(p6.w) + BF_HI(p7.w);
  }
  for (; e + 4 <= hi; e += 4) {
    int n0 = csr[e + 0], n1 = csr[e + 1], n2 = csr[e + 2], n3 = csr[e + 3];
    uint4 p0 = *(const uint4*)(y + (size_t)n0 * 16 + q8);
    uint4 p1 = *(const uint4*)(y + (size_t)n1 * 16 + q8);
    uint4 p2 = *(const uint4*)(y + (size_t)n2 * 16 + q8);
    uint4 p3 = *(const uint4*)(y + (size_t)n3 * 16 + q8);
    a0 += BF_LO(p0.x) + BF_LO(p1.x) + BF_LO(p2.x) + BF_LO(p3.x);
    a1 += BF_HI(p0.x) + BF_HI(p1.x) + BF_HI(p2.x) + BF_HI(p3.x);
    a2 += BF_LO(p0.y) + BF_LO(p1.y) + BF_LO(p2.y) + BF_LO(p3.y);
    a3 += BF_HI(p0.y) + BF_HI(p1.y) + BF_HI(p2.y) + BF_HI(p3.y);
    a4 += BF_LO(p0.z) + BF_LO(p1.z) + BF_LO(p2.z) + BF_LO(p3.z);
    a5 += BF_HI(p0.z) + BF_HI(p1.z) + BF_HI(p2.z) + BF_HI(p3.z);
    a6 += BF_LO(p0.w) + BF_LO(p1.w) + BF_LO(p2.w) + BF_LO(p3.w);
    a7 += BF_HI(p0.w) + BF_HI(p1.w) + BF_HI(p2.w) + BF_HI(p3.w);
  }
  for (; e < hi; e++) {
    int nb = csr[e];
    uint4 p = *(const uint4*)(y + (size_t)nb * 16 + q8);
    a0 += BF_LO(p.x); a1 += BF_HI(p.x);
    a2 += BF_LO(p.y); a3 += BF_HI(p.y);
    a4 += BF_LO(p.z); a5 += BF_HI(p.z);
    a6 += BF_LO(p.w); a7 += BF_HI(p.w);
  }
  if (valid && xres) {
    const float4* rp = (const float4*)(xres + (size_t)i * CH + chanbase + q8);
    float4 r0 = rp[0], r1 = rp[1];
    a0 += r0.x; a1 += r0.y; a2 += r0.z; a3 += r0.w;
    a4 += r1.x; a5 += r1.y; a6 += r1.z; a7 += r1.w;
  }
  if (valid) {
    float4* op = (float4*)(out + (size_t)i * CH + chanbase + q8);
    op[0] = make_float4(a0, a1, a2, a3);
    op[1] = make_float4(a4, a5, a6, a7);
  }
  if (stats) {
    float s0 = a0 * a0, s1 = a1 * a1, s2 = a2 * a2, s3 = a3 * a3;
    float s4 = a4 * a4, s5 = a5 * a5, s6 = a6 * a6, s7 = a7 * a7;
#pragma unroll
    for (int o = 32; o >= 2; o >>= 1) {
      a0 += __shfl_down(a0, o); a1 += __shfl_down(a1, o);
      a2 += __shfl_down(a2, o); a3 += __shfl_down(a3, o);
      a4 += __shfl_down(a4, o); a5 += __shfl_down(a5, o);
      a6 += __shfl_down(a6, o); a7 += __shfl_down(a7, o);
      s0 += __shfl_down(s0, o); s1 += __shfl_down(s1, o);
      s2 += __shfl_down(s2, o); s3 += __shfl_down(s3, o);
      s4 += __shfl_down(s4, o); s5 += __shfl_down(s5, o);
      s6 += __shfl_down(s6, o); s7 += __shfl_down(s7, o);
    }
    if ((tid & 63) < 2) {
      int cb = chanbase + q8;
      atomicAdd(&ssum[cb + 0], a0); atomicAdd(&ssum[cb + 1], a1);
      atomicAdd(&ssum[cb + 2], a2); atomicAdd(&ssum[cb + 3], a3);
      atomicAdd(&ssum[cb + 4], a4); atomicAdd(&ssum[cb + 5], a5);
      atomicAdd(&ssum[cb + 6], a6); atomicAdd(&ssum[cb + 7], a7);
      atomicAdd(&sssq[cb + 0], s0); atomicAdd(&sssq[cb + 1], s1);
      atomicAdd(&sssq[cb + 2], s2); atomicAdd(&sssq[cb + 3], s3);
      atomicAdd(&sssq[cb + 4], s4); atomicAdd(&sssq[cb + 5], s5);
      atomicAdd(&sssq[cb + 6], s6); atomicAdd(&sssq[cb + 7], s7);
    }
    __syncthreads();
    if (tid < 16) {
      int c = chanbase + tid;
      atomicAdd(&stats[c], ssum[c]);
      atomicAdd(&stats[CH + c], sssq[c]);
    }
  }
}

// ---------------------------------------------------------------------------
// MLP head, hidden-split x4 (R6 version — measured 260->185 µs)
// ---------------------------------------------------------------------------
__global__ void __launch_bounds__(256) score_kernel(
    const float* __restrict__ x, const int* __restrict__ indices,
    const int* __restrict__ assignment,
    const float* __restrict__ wh, const float* __restrict__ bh,
    const float* __restrict__ wo,
    float* __restrict__ s, int* __restrict__ seg) {
  __shared__ __align__(16) float s_wh[256][36];
  __shared__ float s_wo[256];
  __shared__ float s_bh[256];
  int tid = threadIdx.x;
  int mb = blockIdx.x >> 2;
  int tile = blockIdx.x & 3;
  int t0 = tile * 256;
  int m = mb * 256 + tid;
  bool valid = m < M_SEL;
  for (int u = tid; u < CH * 256; u += 256) {
    int k = u >> 8, jj = u & 255;
    s_wh[jj][k] = wh[(size_t)k * HID + t0 + jj];
  }
  s_wo[tid] = wo[t0 + tid];
  s_bh[tid] = bh[t0 + tid];
  __syncthreads();
  if (!valid) return;
  int idx = indices[m];
  float a[CH];
  const float4* xp = (const float4*)(x + (size_t)idx * CH);
#pragma unroll
  for (int q = 0; q < 8; q++) {
    float4 t = xp[q];
    a[4 * q + 0] = fmaxf(t.x, 0.f); a[4 * q + 1] = fmaxf(t.y, 0.f);
    a[4 * q + 2] = fmaxf(t.z, 0.f); a[4 * q + 3] = fmaxf(t.w, 0.f);
  }
  float sacc = 0.f;
  for (int jj = 0; jj < 256; jj++) {
    float h = s_bh[jj];
    const float4* wp = (const float4*)&s_wh[jj][0];
#pragma unroll
    for (int q = 0; q < 8; q++) {
      float4 w = wp[q];
      h += a[4 * q] * w.x + a[4 * q + 1] * w.y + a[4 * q + 2] * w.z + a[4 * q + 3] * w.w;
    }
    sacc += fmaxf(h, 0.f) * s_wo[jj];
  }
  atomicAdd(&s[m], sacc);
  if (tile == 0) seg[m] = assignment[idx];
}

// ---------------------------------------------------------------------------
// Segmented log-softmax
// ---------------------------------------------------------------------------
__device__ __forceinline__ int lower_bound_dev(const int* a, int n, int key) {
  int lo = 0, hi = n;
  while (lo < hi) { int mid = (lo + hi) >> 1; if (a[mid] < key) lo = mid + 1; else hi = mid; }
  return lo;
}

__global__ void __launch_bounds__(256) logsoftmax_kernel(
    const float* __restrict__ s, const int* __restrict__ seg, float* __restrict__ out) {
  __shared__ float red[256];
  __shared__ int bounds[2];
  int tid = threadIdx.x;
  int b = blockIdx.x;
  if (tid == 0) {
    bounds[0] = lower_bound_dev(seg, M_SEL, b);
    bounds[1] = lower_bound_dev(seg, M_SEL, b + 1);
  }
  __syncthreads();
  int lo = bounds[0], hi = bounds[1];
  float mx = -INFINITY;
  for (int i = lo + tid; i < hi; i += 256) mx = fmaxf(mx, s[i]);
  red[tid] = mx; __syncthreads();
  for (int o = 128; o > 0; o >>= 1) { if (tid < o) red[tid] = fmaxf(red[tid], red[tid + o]); __syncthreads(); }
  float mxv = red[0];
  __syncthreads();
  float sum = 0.f;
  for (int i = lo + tid; i < hi; i += 256) sum += expf(s[i] - mxv);
  red[tid] = sum; __syncthreads();
  for (int o = 128; o > 0; o >>= 1) { if (tid < o) red[tid] += red[tid + o]; __syncthreads(); }
  float lse = logf(red[0]);
  for (int i = lo + tid; i < hi; i += 256) out[i] = (s[i] - mxv) - lse;
}

// ---------------------------------------------------------------------------
extern "C" void kernel_launch(void* const* d_in, const int* in_sizes, int n_in,
                              void* d_out, int out_size, void* d_ws, size_t ws_size,
                              hipStream_t stream) {
  const int*   assignment = (const int*)d_in[1];
  const int*   nodes      = (const int*)d_in[2];
  const int*   src        = (const int*)d_in[3];
  const int*   dst        = (const int*)d_in[4];
  const int*   indices    = (const int*)d_in[5];
  const float* emb        = (const float*)d_in[6];
  const float* w0_out     = (const float*)d_in[7];
  const float* w0_back    = (const float*)d_in[8];
  const float* bn1_gamma  = (const float*)d_in[9];
  const float* bn1_beta   = (const float*)d_in[10];
  const float* w1_out     = (const float*)d_in[11];
  const float* w1_back    = (const float*)d_in[12];
  const float* bn2_gamma  = (const float*)d_in[13];
  const float* bn2_beta   = (const float*)d_in[14];
  const float* w2_out     = (const float*)d_in[15];
  const float* w2_back    = (const float*)d_in[16];
  const float* wh         = (const float*)d_in[17];
  const float* bh         = (const float*)d_in[18];
  const float* wo         = (const float*)d_in[19];
  float* out = (float*)d_out;

  char* ws = (char*)d_ws;
  size_t off = 0;
  auto alloc = [&](size_t bytes) {
    char* p = ws + off;
    off = (off + bytes + 255) & ~(size_t)255;
    return p;
  };
  // bcnt_in/bcnt_out contiguous in ONE alloc (single memset must cover both)
  int* bcnt_in  = (int*)alloc((size_t)2 * KB * 4); int* bcnt_out = bcnt_in + KB;
  int* boff_in  = (int*)alloc((size_t)(KB + 1) * 4);
  int* boff_out = (int*)alloc((size_t)(KB + 1) * 4);
  int* gcur_in  = (int*)alloc((size_t)KB * 4);
  int* gcur_out = (int*)alloc((size_t)KB * 4);
  int* off_in   = (int*)alloc((size_t)(N_NODES + 1) * 4);
  int* off_out  = (int*)alloc((size_t)(N_NODES + 1) * 4);
  float* stats  = (float*)alloc((size_t)16 * 64 * 4);
  int* csr_in   = (int*)alloc((size_t)N_EDGES * 4);
  int* csr_out  = (int*)alloc((size_t)N_EDGES * 4);
  int* perm_in  = (int*)alloc((size_t)NWIN * 128 * 4);
  int* perm_out = (int*)alloc((size_t)NWIN * 128 * 4);
  unsigned short* y_out  = (unsigned short*)alloc((size_t)N_NODES * 16 * 2);
  unsigned short* y_back = (unsigned short*)alloc((size_t)N_NODES * 16 * 2);
  float* xb = (float*)alloc((size_t)N_NODES * CH * 4);
  float* hb = (float*)alloc((size_t)N_NODES * CH * 4);
  float* sb = (float*)alloc((size_t)M_SEL * 4);
  int* segb = (int*)alloc((size_t)M_SEL * 4);
  // staging aliases xb (consumed by build_kernel before xb is first written)
  unsigned* staging_in  = (unsigned*)xb;
  unsigned* staging_out = (unsigned*)xb + N_EDGES;

  hipMemsetAsync(bcnt_in, 0, (size_t)2 * KB * 4, stream);
  hipMemsetAsync(stats, 0, (size_t)16 * 64 * 4, stream);
  hipMemsetAsync(sb, 0, (size_t)M_SEL * 4, stream);

  bin_count_kernel<<<1024, 256, 0, stream>>>(src, dst, bcnt_in, bcnt_out);
  bucket_scan_kernel<<<1, 256, 0, stream>>>(bcnt_in, boff_in, gcur_in,
                                            bcnt_out, boff_out, gcur_out);
  dim3 gStage((N_EDGES + 4095) / 4096, 2);
  stage_kernel<<<gStage, 256, 0, stream>>>(src, dst, gcur_in, staging_in,
                                           gcur_out, staging_out);
  dim3 gBuild(KB, 2);
  build_kernel<<<gBuild, 256, 0, stream>>>(staging_in, boff_in, off_in, csr_in,
                                           staging_out, boff_out, off_out, csr_out);
  dim3 gSort(NWIN, 2);
  wsort_kernel<<<gSort, 128, 0, stream>>>(off_in, perm_in, off_out, perm_out);

  const int gA = (N_NODES + 255) / 256;
  dim3 gAgg(NWIN, 2);
  auto agg_pass = [&](const float* xres, float* outb, float* st) {
    agg_dir_kernel<<<gAgg, 256, 0, stream>>>(y_out, y_back, xres, outb,
                                             off_in, csr_in, off_out, csr_out,
                                             perm_in, perm_out, st);
  };

  emb_mm_kernel<<<gA, 256, 0, stream>>>(nodes, emb, w0_out, w0_back, y_out, y_back);
  agg_pass(nullptr, xb, stats + 0 * 64);
  for (int l = 0; l < NL; l++) {
    bn_relu_mm_kernel<<<gA, 256, 0, stream>>>(xb, stats + (2 * l) * 64,
                                              bn1_gamma + l * CH, bn1_beta + l * CH,
                                              w1_out + l * CH * 16, w1_back + l * CH * 16,
                                              y_out, y_back);
    agg_pass(nullptr, hb, stats + (2 * l + 1) * 64);
    bn_relu_mm_kernel<<<gA, 256, 0, stream>>>(hb, stats + (2 * l + 1) * 64,
                                              bn2_gamma + l * CH, bn2_beta + l * CH,
                                              w2_out + l * CH * 16, w2_back + l * CH * 16,
                                              y_out, y_back);
    agg_pass(xb, xb, (l < NL - 1) ? (stats + (2 * l + 2) * 64) : nullptr);
  }
  score_kernel<<<4 * ((M_SEL + 255) / 256), 256, 0, stream>>>(
      xb, indices, assignment, wh, bh, wo, sb, segb);
  logsoftmax_kernel<<<NEX, 256, 0, stream>>>(sb, segb, out);
}

// Round 11
// 2251.450 us; speedup vs baseline: 1.0687x; 1.0687x over previous
//
#include <hip/hip_runtime.h>
#include <math.h>

#define N_NODES 200000
#define N_EDGES 3200000
#define M_SEL   100000
#define NEX     32
#define NT      11
#define CH      32
#define HID     1024
#define NL      8
#define BN_EPS  1e-5f

#define BSHIFT  9
#define BSIZE   512
#define KB      391
#define PAYMASK 0x3FFFF

typedef __attribute__((ext_vector_type(8))) short bf16x8;
typedef __attribute__((ext_vector_type(4))) float f32x4;

// bf16 helpers (RNE)
__device__ __forceinline__ unsigned bf16_bits(float f) {
  unsigned u = __float_as_uint(f);
  return (u + 0x7fffu + ((u >> 16) & 1u)) >> 16;
}
__device__ __forceinline__ unsigned pack_bf2(float lo, float hi) {
  return bf16_bits(lo) | (bf16_bits(hi) << 16);
}
#define BF_LO(u) __uint_as_float((u) << 16)
#define BF_HI(u) __uint_as_float((u) & 0xffff0000u)

// ---------------------------------------------------------------------------
// CSR build (radix-partition, R5 — measured good)
// ---------------------------------------------------------------------------
__global__ void __launch_bounds__(256) bin_count_kernel(
    const int* __restrict__ src, const int* __restrict__ dst,
    int* __restrict__ bcnt_in, int* __restrict__ bcnt_out) {
  __shared__ int h_in[KB], h_out[KB];
  int tid = threadIdx.x;
  for (int i = tid; i < KB; i += 256) { h_in[i] = 0; h_out[i] = 0; }
  __syncthreads();
  for (int e = blockIdx.x * 256 + tid; e < N_EDGES; e += gridDim.x * 256) {
    atomicAdd(&h_in[dst[e] >> BSHIFT], 1);
    atomicAdd(&h_out[src[e] >> BSHIFT], 1);
  }
  __syncthreads();
  for (int b = tid; b < KB; b += 256) {
    if (h_in[b])  atomicAdd(&bcnt_in[b], h_in[b]);
    if (h_out[b]) atomicAdd(&bcnt_out[b], h_out[b]);
  }
}

__global__ void __launch_bounds__(256) bucket_scan_kernel(
    const int* __restrict__ bcnt_in, int* __restrict__ boff_in, int* __restrict__ gcur_in,
    const int* __restrict__ bcnt_out, int* __restrict__ boff_out, int* __restrict__ gcur_out) {
  __shared__ int s[512];
  __shared__ int wtot[4];
  int tid = threadIdx.x;
  int lane = tid & 63, wid = tid >> 6;
  for (int dir = 0; dir < 2; dir++) {
    const int* bcnt = dir ? bcnt_out : bcnt_in;
    int* boff = dir ? boff_out : boff_in;
    int* gcur = dir ? gcur_out : gcur_in;
    int i0 = 2 * tid, i1 = 2 * tid + 1;
    int a0 = (i0 < KB) ? bcnt[i0] : 0;
    int a1 = (i1 < KB) ? bcnt[i1] : 0;
    int pair = a0 + a1;
    int incl = pair;
#pragma unroll
    for (int o = 1; o < 64; o <<= 1) { int t = __shfl_up(incl, o); if (lane >= o) incl += t; }
    if (lane == 63) wtot[wid] = incl;
    __syncthreads();
    if (tid == 0) { int r = 0; for (int w = 0; w < 4; w++) { int v = wtot[w]; wtot[w] = r; r += v; } }
    __syncthreads();
    int exclp = incl - pair + wtot[wid];
    s[i0] = exclp;
    s[i1] = exclp + a0;
    __syncthreads();
    for (int b = tid; b < KB; b += 256) { boff[b] = s[b]; gcur[b] = s[b]; }
    if (i0 == KB - 1) boff[KB] = s[i0] + a0;
    if (i1 == KB - 1) boff[KB] = s[i1] + a1;
    __syncthreads();
  }
}

__global__ void __launch_bounds__(256) stage_kernel(
    const int* __restrict__ src, const int* __restrict__ dst,
    int* __restrict__ gcur_in, unsigned* __restrict__ staging_in,
    int* __restrict__ gcur_out, unsigned* __restrict__ staging_out) {
  __shared__ int cnt[KB], cur[KB];
  int tid = threadIdx.x;
  int dir = blockIdx.y;
  const int* key = dir ? src : dst;
  const int* pay = dir ? dst : src;
  int* gcur = dir ? gcur_out : gcur_in;
  unsigned* staging = dir ? staging_out : staging_in;
  for (int i = tid; i < KB; i += 256) cnt[i] = 0;
  __syncthreads();
  int e0 = blockIdx.x * 4096;
#pragma unroll
  for (int j = 0; j < 16; j++) {
    int e = e0 + j * 256 + tid;
    if (e < N_EDGES) atomicAdd(&cnt[key[e] >> BSHIFT], 1);
  }
  __syncthreads();
  for (int b = tid; b < KB; b += 256) {
    int c = cnt[b];
    cur[b] = c ? atomicAdd(&gcur[b], c) : 0;
  }
  __syncthreads();
#pragma unroll
  for (int j = 0; j < 16; j++) {
    int e = e0 + j * 256 + tid;
    if (e < N_EDGES) {
      int k = key[e];
      int b = k >> BSHIFT;
      int p = atomicAdd(&cur[b], 1);
      staging[p] = ((unsigned)(k & (BSIZE - 1)) << 18) | (unsigned)pay[e];
    }
  }
}

__global__ void __launch_bounds__(256) build_kernel(
    const unsigned* __restrict__ staging_in, const int* __restrict__ boff_in,
    int* __restrict__ off_in, int* __restrict__ csr_in,
    const unsigned* __restrict__ staging_out, const int* __restrict__ boff_out,
    int* __restrict__ off_out, int* __restrict__ csr_out) {
  __shared__ int cnt[BSIZE];
  __shared__ int wtot[4];
  int tid = threadIdx.x;
  int b = blockIdx.x;
  int dir = blockIdx.y;
  const unsigned* staging = dir ? staging_out : staging_in;
  const int* boff = dir ? boff_out : boff_in;
  int* off = dir ? off_out : off_in;
  int* csr = dir ? csr_out : csr_in;
  int ebase = boff[b], eend = boff[b + 1];
  int node_base = b << BSHIFT;
  int nnodes = min(BSIZE, N_NODES - node_base);
  cnt[2 * tid] = 0; cnt[2 * tid + 1] = 0;
  __syncthreads();
  for (int e = ebase + tid; e < eend; e += 256)
    atomicAdd(&cnt[staging[e] >> 18], 1);
  __syncthreads();
  int i0 = 2 * tid, i1 = 2 * tid + 1;
  int a0 = cnt[i0], a1 = cnt[i1];
  int pair = a0 + a1;
  int lane = tid & 63, wid = tid >> 6;
  int incl = pair;
#pragma unroll
  for (int o = 1; o < 64; o <<= 1) { int t = __shfl_up(incl, o); if (lane >= o) incl += t; }
  if (lane == 63) wtot[wid] = incl;
  __syncthreads();
  if (tid == 0) { int r = 0; for (int w = 0; w < 4; w++) { int v = wtot[w]; wtot[w] = r; r += v; } }
  __syncthreads();
  int exclp = incl - pair + wtot[wid];
  cnt[i0] = exclp;
  cnt[i1] = exclp + a0;
  __syncthreads();
  for (int i = tid; i < nnodes; i += 256) off[node_base + i] = ebase + cnt[i];
  if (b == KB - 1 && tid == 0) off[N_NODES] = boff[KB];
  __syncthreads();
  for (int e = ebase + tid; e < eend; e += 256) {
    unsigned rec = staging[e];
    int p = atomicAdd(&cnt[rec >> 18], 1);
    csr[ebase + p] = (int)(rec & PAYMASK);
  }
}

// ---------------------------------------------------------------------------
// Prep: swizzle wh (32x1024 f32) into mfma B-fragment order, bf16.
// wh_frag[t*512 + lane*8 + i] = bf16(wh[k=(lane>>4)*8+i][n=t*16+(lane&15)])
// ---------------------------------------------------------------------------
__global__ void __launch_bounds__(256) prep_whfrag_kernel(
    const float* __restrict__ wh, unsigned short* __restrict__ wh_frag) {
  int id = blockIdx.x * 256 + threadIdx.x;
  if (id >= 64 * 64 * 8) return;
  int t = id >> 9;
  int rem = id & 511;
  int lane = rem >> 3;
  int i = rem & 7;
  int k = (lane >> 4) * 8 + i;
  int n = t * 16 + (lane & 15);
  wh_frag[id] = (unsigned short)bf16_bits(wh[(size_t)k * HID + n]);
}

// ---------------------------------------------------------------------------
// Pack 32 fp32 acc channels into split bf16 arrays (16 ch each, 32 B rows)
// ---------------------------------------------------------------------------
__device__ __forceinline__ void store_split(unsigned short* y_out,
                                            unsigned short* y_back,
                                            int i, const float* acc) {
  uint4 t0, t1;
  t0.x = pack_bf2(acc[0], acc[1]);   t0.y = pack_bf2(acc[2], acc[3]);
  t0.z = pack_bf2(acc[4], acc[5]);   t0.w = pack_bf2(acc[6], acc[7]);
  t1.x = pack_bf2(acc[8], acc[9]);   t1.y = pack_bf2(acc[10], acc[11]);
  t1.z = pack_bf2(acc[12], acc[13]); t1.w = pack_bf2(acc[14], acc[15]);
  uint4* po = (uint4*)(y_out + (size_t)i * 16);
  po[0] = t0; po[1] = t1;
  t0.x = pack_bf2(acc[16], acc[17]); t0.y = pack_bf2(acc[18], acc[19]);
  t0.z = pack_bf2(acc[20], acc[21]); t0.w = pack_bf2(acc[22], acc[23]);
  t1.x = pack_bf2(acc[24], acc[25]); t1.y = pack_bf2(acc[26], acc[27]);
  t1.z = pack_bf2(acc[28], acc[29]); t1.w = pack_bf2(acc[30], acc[31]);
  uint4* pb = (uint4*)(y_back + (size_t)i * 16);
  pb[0] = t0; pb[1] = t1;
}

// ---------------------------------------------------------------------------
// A0: x0 = emb[nodes]; y = x0 @ [w0_out | w0_back]
// ---------------------------------------------------------------------------
__global__ void __launch_bounds__(256) emb_mm_kernel(
    const int* __restrict__ nodes, const float* __restrict__ emb,
    const float* __restrict__ w_out, const float* __restrict__ w_back,
    unsigned short* __restrict__ y_out, unsigned short* __restrict__ y_back) {
  __shared__ float W[CH][CH];
  __shared__ float Esh[NT * CH];
  int tid = threadIdx.x;
  for (int t = tid; t < CH * CH; t += blockDim.x) {
    int k = t >> 5, j = t & 31;
    W[k][j] = (j < 16) ? w_out[k * 16 + j] : w_back[k * 16 + j - 16];
  }
  for (int t = tid; t < NT * CH; t += blockDim.x) Esh[t] = emb[t];
  __syncthreads();
  int i = blockIdx.x * blockDim.x + tid;
  if (i >= N_NODES) return;
  int tn = nodes[i];
  float v[CH];
#pragma unroll
  for (int k = 0; k < CH; k++) v[k] = Esh[tn * CH + k];
  float acc[CH];
#pragma unroll
  for (int j = 0; j < CH; j++) acc[j] = 0.f;
#pragma unroll
  for (int k = 0; k < CH; k++) {
    float vk = v[k];
#pragma unroll
    for (int j = 0; j < CH; j++) acc[j] += vk * W[k][j];
  }
  store_split(y_out, y_back, i, acc);
}

// ---------------------------------------------------------------------------
// A: y = relu(bn(x)) @ [w_out | w_back]
// ---------------------------------------------------------------------------
__global__ void __launch_bounds__(256) bn_relu_mm_kernel(
    const float* __restrict__ xin, const float* __restrict__ stats,
    const float* __restrict__ gamma, const float* __restrict__ beta,
    const float* __restrict__ w_out, const float* __restrict__ w_back,
    unsigned short* __restrict__ y_out, unsigned short* __restrict__ y_back) {
  __shared__ float W[CH][CH];
  __shared__ float sc[CH], sh[CH];
  int tid = threadIdx.x;
  for (int t = tid; t < CH * CH; t += blockDim.x) {
    int k = t >> 5, j = t & 31;
    W[k][j] = (j < 16) ? w_out[k * 16 + j] : w_back[k * 16 + j - 16];
  }
  if (tid < CH) {
    float m  = stats[tid] * (1.0f / N_NODES);
    float s2 = stats[CH + tid] * (1.0f / N_NODES);
    float var = s2 - m * m;
    float scale = gamma[tid] * rsqrtf(var + BN_EPS);
    sc[tid] = scale;
    sh[tid] = beta[tid] - m * scale;
  }
  __syncthreads();
  int i = blockIdx.x * blockDim.x + tid;
  if (i >= N_NODES) return;
  const float4* xp = (const float4*)(xin + (size_t)i * CH);
  float v[CH];
#pragma unroll
  for (int q = 0; q < 8; q++) {
    float4 t = xp[q];
    v[4 * q + 0] = fmaxf(t.x * sc[4 * q + 0] + sh[4 * q + 0], 0.f);
    v[4 * q + 1] = fmaxf(t.y * sc[4 * q + 1] + sh[4 * q + 1], 0.f);
    v[4 * q + 2] = fmaxf(t.z * sc[4 * q + 2] + sh[4 * q + 2], 0.f);
    v[4 * q + 3] = fmaxf(t.w * sc[4 * q + 3] + sh[4 * q + 3], 0.f);
  }
  float acc[CH];
#pragma unroll
  for (int j = 0; j < CH; j++) acc[j] = 0.f;
#pragma unroll
  for (int k = 0; k < CH; k++) {
    float vk = v[k];
#pragma unroll
    for (int j = 0; j < CH; j++) acc[j] += vk * W[k][j];
  }
  store_split(y_out, y_back, i, acc);
}

// ---------------------------------------------------------------------------
// B: node-parallel gather aggregation (R9, measured best: ~105 µs/dispatch,
// at the ~2 lines/cyc/XCD LLC random-line service ceiling).
// ---------------------------------------------------------------------------
__global__ void __launch_bounds__(256) agg_dir_kernel(
    const unsigned short* __restrict__ y_out, const unsigned short* __restrict__ y_back,
    const float* __restrict__ xres, float* __restrict__ out,
    const int* __restrict__ off_in, const int* __restrict__ csr_in,
    const int* __restrict__ off_out, const int* __restrict__ csr_out,
    float* __restrict__ stats) {
  __shared__ float ssum[CH], sssq[CH];
  int tid = threadIdx.x;
  if (tid < CH) { ssum[tid] = 0.f; sssq[tid] = 0.f; }
  __syncthreads();
  int dir = blockIdx.y;
  const unsigned short* y = dir ? y_back : y_out;
  const int* off = dir ? off_out : off_in;
  const int* csr = dir ? csr_out : csr_in;
  int chanbase = dir * 16;
  int t = blockIdx.x * 256 + tid;
  bool valid = t < 2 * N_NODES;
  int q = t & 1;
  int i = valid ? (t >> 1) : 0;
  int lo = 0, hi = 0;
  if (valid) { lo = off[i]; hi = off[i + 1]; }
  int q8 = q * 8;
  float a0 = 0.f, a1 = 0.f, a2 = 0.f, a3 = 0.f;
  float a4 = 0.f, a5 = 0.f, a6 = 0.f, a7 = 0.f;
  int e = lo;
  for (; e + 8 <= hi; e += 8) {
    int n0 = csr[e + 0], n1 = csr[e + 1], n2 = csr[e + 2], n3 = csr[e + 3];
    int n4 = csr[e + 4], n5 = csr[e + 5], n6 = csr[e + 6], n7 = csr[e + 7];
    uint4 p0 = *(const uint4*)(y + (size_t)n0 * 16 + q8);
    uint4 p1 = *(const uint4*)(y + (size_t)n1 * 16 + q8);
    uint4 p2 = *(const uint4*)(y + (size_t)n2 * 16 + q8);
    uint4 p3 = *(const uint4*)(y + (size_t)n3 * 16 + q8);
    uint4 p4 = *(const uint4*)(y + (size_t)n4 * 16 + q8);
    uint4 p5 = *(const uint4*)(y + (size_t)n5 * 16 + q8);
    uint4 p6 = *(const uint4*)(y + (size_t)n6 * 16 + q8);
    uint4 p7 = *(const uint4*)(y + (size_t)n7 * 16 + q8);
    a0 += BF_LO(p0.x) + BF_LO(p1.x) + BF_LO(p2.x) + BF_LO(p3.x)
        + BF_LO(p4.x) + BF_LO(p5.x) + BF_LO(p6.x) + BF_LO(p7.x);
    a1 += BF_HI(p0.x) + BF_HI(p1.x) + BF_HI(p2.x) + BF_HI(p3.x)
        + BF_HI(p4.x) + BF_HI(p5.x) + BF_HI(p6.x) + BF_HI(p7.x);
    a2 += BF_LO(p0.y) + BF_LO(p1.y) + BF_LO(p2.y) + BF_LO(p3.y)
        + BF_LO(p4.y) + BF_LO(p5.y) + BF_LO(p6.y) + BF_LO(p7.y);
    a3 += BF_HI(p0.y) + BF_HI(p1.y) + BF_HI(p2.y) + BF_HI(p3.y)
        + BF_HI(p4.y) + BF_HI(p5.y) + BF_HI(p6.y) + BF_HI(p7.y);
    a4 += BF_LO(p0.z) + BF_LO(p1.z) + BF_LO(p2.z) + BF_LO(p3.z)
        + BF_LO(p4.z) + BF_LO(p5.z) + BF_LO(p6.z) + BF_LO(p7.z);
    a5 += BF_HI(p0.z) + BF_HI(p1.z) + BF_HI(p2.z) + BF_HI(p3.z)
        + BF_HI(p4.z) + BF_HI(p5.z) + BF_HI(p6.z) + BF_HI(p7.z);
    a6 += BF_LO(p0.w) + BF_LO(p1.w) + BF_LO(p2.w) + BF_LO(p3.w)
        + BF_LO(p4.w) + BF_LO(p5.w) + BF_LO(p6.w) + BF_LO(p7.w);
    a7 += BF_HI(p0.w) + BF_HI(p1.w) + BF_HI(p2.w) + BF_HI(p3.w)
        + BF_HI(p4.w) + BF_HI(p5.w) + BF_HI(p6.w) + BF_HI(p7.w);
  }
  for (; e + 4 <= hi; e += 4) {
    int n0 = csr[e + 0], n1 = csr[e + 1], n2 = csr[e + 2], n3 = csr[e + 3];
    uint4 p0 = *(const uint4*)(y + (size_t)n0 * 16 + q8);
    uint4 p1 = *(const uint4*)(y + (size_t)n1 * 16 + q8);
    uint4 p2 = *(const uint4*)(y + (size_t)n2 * 16 + q8);
    uint4 p3 = *(const uint4*)(y + (size_t)n3 * 16 + q8);
    a0 += BF_LO(p0.x) + BF_LO(p1.x) + BF_LO(p2.x) + BF_LO(p3.x);
    a1 += BF_HI(p0.x) + BF_HI(p1.x) + BF_HI(p2.x) + BF_HI(p3.x);
    a2 += BF_LO(p0.y) + BF_LO(p1.y) + BF_LO(p2.y) + BF_LO(p3.y);
    a3 += BF_HI(p0.y) + BF_HI(p1.y) + BF_HI(p2.y) + BF_HI(p3.y);
    a4 += BF_LO(p0.z) + BF_LO(p1.z) + BF_LO(p2.z) + BF_LO(p3.z);
    a5 += BF_HI(p0.z) + BF_HI(p1.z) + BF_HI(p2.z) + BF_HI(p3.z);
    a6 += BF_LO(p0.w) + BF_LO(p1.w) + BF_LO(p2.w) + BF_LO(p3.w);
    a7 += BF_HI(p0.w) + BF_HI(p1.w) + BF_HI(p2.w) + BF_HI(p3.w);
  }
  for (; e < hi; e++) {
    int nb = csr[e];
    uint4 p = *(const uint4*)(y + (size_t)nb * 16 + q8);
    a0 += BF_LO(p.x); a1 += BF_HI(p.x);
    a2 += BF_LO(p.y); a3 += BF_HI(p.y);
    a4 += BF_LO(p.z); a5 += BF_HI(p.z);
    a6 += BF_LO(p.w); a7 += BF_HI(p.w);
  }
  if (valid && xres) {
    const float4* rp = (const float4*)(xres + (size_t)i * CH + chanbase + q8);
    float4 r0 = rp[0], r1 = rp[1];
    a0 += r0.x; a1 += r0.y; a2 += r0.z; a3 += r0.w;
    a4 += r1.x; a5 += r1.y; a6 += r1.z; a7 += r1.w;
  }
  if (valid) {
    float4* op = (float4*)(out + (size_t)i * CH + chanbase + q8);
    op[0] = make_float4(a0, a1, a2, a3);
    op[1] = make_float4(a4, a5, a6, a7);
  }
  if (stats) {
    float s0 = a0 * a0, s1 = a1 * a1, s2 = a2 * a2, s3 = a3 * a3;
    float s4 = a4 * a4, s5 = a5 * a5, s6 = a6 * a6, s7 = a7 * a7;
#pragma unroll
    for (int o = 32; o >= 2; o >>= 1) {
      a0 += __shfl_down(a0, o); a1 += __shfl_down(a1, o);
      a2 += __shfl_down(a2, o); a3 += __shfl_down(a3, o);
      a4 += __shfl_down(a4, o); a5 += __shfl_down(a5, o);
      a6 += __shfl_down(a6, o); a7 += __shfl_down(a7, o);
      s0 += __shfl_down(s0, o); s1 += __shfl_down(s1, o);
      s2 += __shfl_down(s2, o); s3 += __shfl_down(s3, o);
      s4 += __shfl_down(s4, o); s5 += __shfl_down(s5, o);
      s6 += __shfl_down(s6, o); s7 += __shfl_down(s7, o);
    }
    if ((tid & 63) < 2) {
      int cb = chanbase + q8;
      atomicAdd(&ssum[cb + 0], a0); atomicAdd(&ssum[cb + 1], a1);
      atomicAdd(&ssum[cb + 2], a2); atomicAdd(&ssum[cb + 3], a3);
      atomicAdd(&ssum[cb + 4], a4); atomicAdd(&ssum[cb + 5], a5);
      atomicAdd(&ssum[cb + 6], a6); atomicAdd(&ssum[cb + 7], a7);
      atomicAdd(&sssq[cb + 0], s0); atomicAdd(&sssq[cb + 1], s1);
      atomicAdd(&sssq[cb + 2], s2); atomicAdd(&sssq[cb + 3], s3);
      atomicAdd(&sssq[cb + 4], s4); atomicAdd(&sssq[cb + 5], s5);
      atomicAdd(&sssq[cb + 6], s6); atomicAdd(&sssq[cb + 7], s7);
    }
    __syncthreads();
    if (tid < 16) {
      int c = chanbase + tid;
      atomicAdd(&stats[c], ssum[c]);
      atomicAdd(&stats[CH + c], sssq[c]);
    }
  }
}

// ---------------------------------------------------------------------------
// MLP head via MFMA: s[m] = sum_n relu( (relu(x[idx]) @ wh)[n] + bh[n] )*wo[n]
// Block = 256 thr = 4 waves; 64 rows/block (16/wave). K=32 in ONE
// mfma_f32_16x16x32_bf16. A from LDS (A[m=lane&15][k=quad*8+j]); B from
// pre-swizzled wh_frag (coalesced 16 B/lane/step). C/D: col=lane&15,
// row=quad*4+reg (verified layout). Epilogue fused; one shfl-xor reduce.
// ---------------------------------------------------------------------------
__global__ void __launch_bounds__(256) score_mfma_kernel(
    const float* __restrict__ x, const int* __restrict__ indices,
    const int* __restrict__ assignment,
    const unsigned short* __restrict__ wh_frag, const float* __restrict__ bh,
    const float* __restrict__ wo,
    float* __restrict__ s, int* __restrict__ seg) {
  __shared__ __align__(16) unsigned short a_lds[64 * 32];  // 4 KB
  __shared__ float bh_lds[HID];
  __shared__ float wo_lds[HID];
  int tid = threadIdx.x;
  int m0 = blockIdx.x * 64;
  // stage bh/wo
#pragma unroll
  for (int u = 0; u < 4; u++) {
    bh_lds[u * 256 + tid] = bh[u * 256 + tid];
    wo_lds[u * 256 + tid] = wo[u * 256 + tid];
  }
  // stage A: thread -> (row r = tid>>2, 8-ch part = tid&3)
  {
    int r = tid >> 2, part = tid & 3;
    int m = m0 + r;
    unsigned short* dstp = &a_lds[r * 32 + part * 8];
    if (m < M_SEL) {
      int idx = indices[m];
      const float4* xp = (const float4*)(x + (size_t)idx * CH + part * 8);
      float4 v0 = xp[0], v1 = xp[1];
      uint4 packed;
      packed.x = pack_bf2(fmaxf(v0.x, 0.f), fmaxf(v0.y, 0.f));
      packed.y = pack_bf2(fmaxf(v0.z, 0.f), fmaxf(v0.w, 0.f));
      packed.z = pack_bf2(fmaxf(v1.x, 0.f), fmaxf(v1.y, 0.f));
      packed.w = pack_bf2(fmaxf(v1.z, 0.f), fmaxf(v1.w, 0.f));
      *(uint4*)dstp = packed;
      if (part == 0) seg[m] = assignment[idx];
    } else {
      *(uint4*)dstp = make_uint4(0, 0, 0, 0);
    }
  }
  __syncthreads();
  int w = tid >> 6;          // wave 0..3, rows w*16..w*16+15
  int lane = tid & 63;
  int quad = lane >> 4;
  int col = lane & 15;
  bf16x8 afrag = *(const bf16x8*)&a_lds[(w * 16 + col) * 32 + quad * 8];
  float racc0 = 0.f, racc1 = 0.f, racc2 = 0.f, racc3 = 0.f;
  for (int t = 0; t < 64; t++) {
    bf16x8 bfrag = *(const bf16x8*)&wh_frag[(size_t)(t * 64 + lane) * 8];
    f32x4 c = __builtin_amdgcn_mfma_f32_16x16x32_bf16(afrag, bfrag,
                                                      (f32x4){0.f, 0.f, 0.f, 0.f},
                                                      0, 0, 0);
    int n = t * 16 + col;
    float bhv = bh_lds[n], wov = wo_lds[n];
    racc0 += fmaxf(c[0] + bhv, 0.f) * wov;
    racc1 += fmaxf(c[1] + bhv, 0.f) * wov;
    racc2 += fmaxf(c[2] + bhv, 0.f) * wov;
    racc3 += fmaxf(c[3] + bhv, 0.f) * wov;
  }
  // reduce across the 16 column lanes (low 4 bits of lane)
#pragma unroll
  for (int o = 8; o >= 1; o >>= 1) {
    racc0 += __shfl_xor(racc0, o);
    racc1 += __shfl_xor(racc1, o);
    racc2 += __shfl_xor(racc2, o);
    racc3 += __shfl_xor(racc3, o);
  }
  if (col == 0) {
    int mrow = m0 + w * 16 + quad * 4;
    if (mrow + 0 < M_SEL) s[mrow + 0] = racc0;
    if (mrow + 1 < M_SEL) s[mrow + 1] = racc1;
    if (mrow + 2 < M_SEL) s[mrow + 2] = racc2;
    if (mrow + 3 < M_SEL) s[mrow + 3] = racc3;
  }
}

// ---------------------------------------------------------------------------
// Segmented log-softmax
// ---------------------------------------------------------------------------
__device__ __forceinline__ int lower_bound_dev(const int* a, int n, int key) {
  int lo = 0, hi = n;
  while (lo < hi) { int mid = (lo + hi) >> 1; if (a[mid] < key) lo = mid + 1; else hi = mid; }
  return lo;
}

__global__ void __launch_bounds__(256) logsoftmax_kernel(
    const float* __restrict__ s, const int* __restrict__ seg, float* __restrict__ out) {
  __shared__ float red[256];
  __shared__ int bounds[2];
  int tid = threadIdx.x;
  int b = blockIdx.x;
  if (tid == 0) {
    bounds[0] = lower_bound_dev(seg, M_SEL, b);
    bounds[1] = lower_bound_dev(seg, M_SEL, b + 1);
  }
  __syncthreads();
  int lo = bounds[0], hi = bounds[1];
  float mx = -INFINITY;
  for (int i = lo + tid; i < hi; i += 256) mx = fmaxf(mx, s[i]);
  red[tid] = mx; __syncthreads();
  for (int o = 128; o > 0; o >>= 1) { if (tid < o) red[tid] = fmaxf(red[tid], red[tid + o]); __syncthreads(); }
  float mxv = red[0];
  __syncthreads();
  float sum = 0.f;
  for (int i = lo + tid; i < hi; i += 256) sum += expf(s[i] - mxv);
  red[tid] = sum; __syncthreads();
  for (int o = 128; o > 0; o >>= 1) { if (tid < o) red[tid] += red[tid + o]; __syncthreads(); }
  float lse = logf(red[0]);
  for (int i = lo + tid; i < hi; i += 256) out[i] = (s[i] - mxv) - lse;
}

// ---------------------------------------------------------------------------
extern "C" void kernel_launch(void* const* d_in, const int* in_sizes, int n_in,
                              void* d_out, int out_size, void* d_ws, size_t ws_size,
                              hipStream_t stream) {
  const int*   assignment = (const int*)d_in[1];
  const int*   nodes      = (const int*)d_in[2];
  const int*   src        = (const int*)d_in[3];
  const int*   dst        = (const int*)d_in[4];
  const int*   indices    = (const int*)d_in[5];
  const float* emb        = (const float*)d_in[6];
  const float* w0_out     = (const float*)d_in[7];
  const float* w0_back    = (const float*)d_in[8];
  const float* bn1_gamma  = (const float*)d_in[9];
  const float* bn1_beta   = (const float*)d_in[10];
  const float* w1_out     = (const float*)d_in[11];
  const float* w1_back    = (const float*)d_in[12];
  const float* bn2_gamma  = (const float*)d_in[13];
  const float* bn2_beta   = (const float*)d_in[14];
  const float* w2_out     = (const float*)d_in[15];
  const float* w2_back    = (const float*)d_in[16];
  const float* wh         = (const float*)d_in[17];
  const float* bh         = (const float*)d_in[18];
  const float* wo         = (const float*)d_in[19];
  float* out = (float*)d_out;

  char* ws = (char*)d_ws;
  size_t off = 0;
  auto alloc = [&](size_t bytes) {
    char* p = ws + off;
    off = (off + bytes + 255) & ~(size_t)255;
    return p;
  };
  // bcnt_in/bcnt_out contiguous in ONE alloc (single memset must cover both)
  int* bcnt_in  = (int*)alloc((size_t)2 * KB * 4); int* bcnt_out = bcnt_in + KB;
  int* boff_in  = (int*)alloc((size_t)(KB + 1) * 4);
  int* boff_out = (int*)alloc((size_t)(KB + 1) * 4);
  int* gcur_in  = (int*)alloc((size_t)KB * 4);
  int* gcur_out = (int*)alloc((size_t)KB * 4);
  int* off_in   = (int*)alloc((size_t)(N_NODES + 1) * 4);
  int* off_out  = (int*)alloc((size_t)(N_NODES + 1) * 4);
  float* stats  = (float*)alloc((size_t)16 * 64 * 4);
  int* csr_in   = (int*)alloc((size_t)N_EDGES * 4);
  int* csr_out  = (int*)alloc((size_t)N_EDGES * 4);
  unsigned short* wh_frag = (unsigned short*)alloc((size_t)64 * 64 * 8 * 2);  // 64 KB
  unsigned short* y_out  = (unsigned short*)alloc((size_t)N_NODES * 16 * 2);
  unsigned short* y_back = (unsigned short*)alloc((size_t)N_NODES * 16 * 2);
  float* xb = (float*)alloc((size_t)N_NODES * CH * 4);
  float* hb = (float*)alloc((size_t)N_NODES * CH * 4);
  float* sb = (float*)alloc((size_t)M_SEL * 4);
  int* segb = (int*)alloc((size_t)M_SEL * 4);
  // staging aliases xb (consumed by build_kernel before xb is first written)
  unsigned* staging_in  = (unsigned*)xb;
  unsigned* staging_out = (unsigned*)xb + N_EDGES;

  hipMemsetAsync(bcnt_in, 0, (size_t)2 * KB * 4, stream);
  hipMemsetAsync(stats, 0, (size_t)16 * 64 * 4, stream);

  bin_count_kernel<<<1024, 256, 0, stream>>>(src, dst, bcnt_in, bcnt_out);
  bucket_scan_kernel<<<1, 256, 0, stream>>>(bcnt_in, boff_in, gcur_in,
                                            bcnt_out, boff_out, gcur_out);
  dim3 gStage((N_EDGES + 4095) / 4096, 2);
  stage_kernel<<<gStage, 256, 0, stream>>>(src, dst, gcur_in, staging_in,
                                           gcur_out, staging_out);
  dim3 gBuild(KB, 2);
  build_kernel<<<gBuild, 256, 0, stream>>>(staging_in, boff_in, off_in, csr_in,
                                           staging_out, boff_out, off_out, csr_out);
  prep_whfrag_kernel<<<(64 * 64 * 8 + 255) / 256, 256, 0, stream>>>(wh, wh_frag);

  const int gA = (N_NODES + 255) / 256;
  dim3 gAgg((2 * N_NODES + 255) / 256, 2);  // (1563, 2), tail-guarded
  auto agg_pass = [&](const float* xres, float* outb, float* st) {
    agg_dir_kernel<<<gAgg, 256, 0, stream>>>(y_out, y_back, xres, outb,
                                             off_in, csr_in, off_out, csr_out, st);
  };

  emb_mm_kernel<<<gA, 256, 0, stream>>>(nodes, emb, w0_out, w0_back, y_out, y_back);
  agg_pass(nullptr, xb, stats + 0 * 64);
  for (int l = 0; l < NL; l++) {
    bn_relu_mm_kernel<<<gA, 256, 0, stream>>>(xb, stats + (2 * l) * 64,
                                              bn1_gamma + l * CH, bn1_beta + l * CH,
                                              w1_out + l * CH * 16, w1_back + l * CH * 16,
                                              y_out, y_back);
    agg_pass(nullptr, hb, stats + (2 * l + 1) * 64);
    bn_relu_mm_kernel<<<gA, 256, 0, stream>>>(hb, stats + (2 * l + 1) * 64,
                                              bn2_gamma + l * CH, bn2_beta + l * CH,
                                              w2_out + l * CH * 16, w2_back + l * CH * 16,
                                              y_out, y_back);
    agg_pass(xb, xb, (l < NL - 1) ? (stats + (2 * l + 2) * 64) : nullptr);
  }
  score_mfma_kernel<<<(M_SEL + 63) / 64, 256, 0, stream>>>(
      xb, indices, assignment, wh_frag, bh, wo, sb, segb);
  logsoftmax_kernel<<<NEX, 256, 0, stream>>>(sb, segb, out);
}

// Round 12
// 2223.957 us; speedup vs baseline: 1.0819x; 1.0124x over previous
//
#include <hip/hip_runtime.h>
#include <math.h>

#define N_NODES 200000
#define N_EDGES 3200000
#define M_SEL   100000
#define NEX     32
#define NT      11
#define CH      32
#define HID     1024
#define NL      8
#define BN_EPS  1e-5f

#define BSHIFT  9
#define BSIZE   512
#define KB      391
#define PAYMASK 0x3FFFF
#define STAGE_BATCH 16384                // edges per stage block (runs ~42 ints)

typedef __attribute__((ext_vector_type(8))) short bf16x8;
typedef __attribute__((ext_vector_type(4))) float f32x4;

// bf16 helpers (RNE)
__device__ __forceinline__ unsigned bf16_bits(float f) {
  unsigned u = __float_as_uint(f);
  return (u + 0x7fffu + ((u >> 16) & 1u)) >> 16;
}
__device__ __forceinline__ unsigned pack_bf2(float lo, float hi) {
  return bf16_bits(lo) | (bf16_bits(hi) << 16);
}
#define BF_LO(u) __uint_as_float((u) << 16)
#define BF_HI(u) __uint_as_float((u) & 0xffff0000u)

// ---------------------------------------------------------------------------
// CSR build (radix-partition)
// ---------------------------------------------------------------------------
__global__ void __launch_bounds__(256) bin_count_kernel(
    const int* __restrict__ src, const int* __restrict__ dst,
    int* __restrict__ bcnt_in, int* __restrict__ bcnt_out) {
  __shared__ int h_in[KB], h_out[KB];
  int tid = threadIdx.x;
  for (int i = tid; i < KB; i += 256) { h_in[i] = 0; h_out[i] = 0; }
  __syncthreads();
  for (int e = blockIdx.x * 256 + tid; e < N_EDGES; e += gridDim.x * 256) {
    atomicAdd(&h_in[dst[e] >> BSHIFT], 1);
    atomicAdd(&h_out[src[e] >> BSHIFT], 1);
  }
  __syncthreads();
  for (int b = tid; b < KB; b += 256) {
    if (h_in[b])  atomicAdd(&bcnt_in[b], h_in[b]);
    if (h_out[b]) atomicAdd(&bcnt_out[b], h_out[b]);
  }
}

__global__ void __launch_bounds__(256) bucket_scan_kernel(
    const int* __restrict__ bcnt_in, int* __restrict__ boff_in, int* __restrict__ gcur_in,
    const int* __restrict__ bcnt_out, int* __restrict__ boff_out, int* __restrict__ gcur_out) {
  __shared__ int s[512];
  __shared__ int wtot[4];
  int tid = threadIdx.x;
  int lane = tid & 63, wid = tid >> 6;
  for (int dir = 0; dir < 2; dir++) {
    const int* bcnt = dir ? bcnt_out : bcnt_in;
    int* boff = dir ? boff_out : boff_in;
    int* gcur = dir ? gcur_out : gcur_in;
    int i0 = 2 * tid, i1 = 2 * tid + 1;
    int a0 = (i0 < KB) ? bcnt[i0] : 0;
    int a1 = (i1 < KB) ? bcnt[i1] : 0;
    int pair = a0 + a1;
    int incl = pair;
#pragma unroll
    for (int o = 1; o < 64; o <<= 1) { int t = __shfl_up(incl, o); if (lane >= o) incl += t; }
    if (lane == 63) wtot[wid] = incl;
    __syncthreads();
    if (tid == 0) { int r = 0; for (int w = 0; w < 4; w++) { int v = wtot[w]; wtot[w] = r; r += v; } }
    __syncthreads();
    int exclp = incl - pair + wtot[wid];
    s[i0] = exclp;
    s[i1] = exclp + a0;
    __syncthreads();
    for (int b = tid; b < KB; b += 256) { boff[b] = s[b]; gcur[b] = s[b]; }
    if (i0 == KB - 1) boff[KB] = s[i0] + a0;
    if (i1 == KB - 1) boff[KB] = s[i1] + a1;
    __syncthreads();
  }
}

// Long runs per (block,bucket): STAGE_BATCH edges/block -> ~42-int runs,
// write amplification ~1.8x instead of ~7x at 4096.
__global__ void __launch_bounds__(256) stage_kernel(
    const int* __restrict__ src, const int* __restrict__ dst,
    int* __restrict__ gcur_in, unsigned* __restrict__ staging_in,
    int* __restrict__ gcur_out, unsigned* __restrict__ staging_out) {
  __shared__ int cnt[KB], cur[KB];
  int tid = threadIdx.x;
  int dir = blockIdx.y;
  const int* key = dir ? src : dst;
  const int* pay = dir ? dst : src;
  int* gcur = dir ? gcur_out : gcur_in;
  unsigned* staging = dir ? staging_out : staging_in;
  for (int i = tid; i < KB; i += 256) cnt[i] = 0;
  __syncthreads();
  int e0 = blockIdx.x * STAGE_BATCH;
  for (int j = 0; j < STAGE_BATCH / 256; j++) {
    int e = e0 + j * 256 + tid;
    if (e < N_EDGES) atomicAdd(&cnt[key[e] >> BSHIFT], 1);
  }
  __syncthreads();
  for (int b = tid; b < KB; b += 256) {
    int c = cnt[b];
    cur[b] = c ? atomicAdd(&gcur[b], c) : 0;
  }
  __syncthreads();
  for (int j = 0; j < STAGE_BATCH / 256; j++) {
    int e = e0 + j * 256 + tid;
    if (e < N_EDGES) {
      int k = key[e];
      int b = k >> BSHIFT;
      int p = atomicAdd(&cur[b], 1);
      staging[p] = ((unsigned)(k & (BSIZE - 1)) << 18) | (unsigned)pay[e];
    }
  }
}

__global__ void __launch_bounds__(256) build_kernel(
    const unsigned* __restrict__ staging_in, const int* __restrict__ boff_in,
    int* __restrict__ off_in, int* __restrict__ csr_in,
    const unsigned* __restrict__ staging_out, const int* __restrict__ boff_out,
    int* __restrict__ off_out, int* __restrict__ csr_out) {
  __shared__ int cnt[BSIZE];
  __shared__ int wtot[4];
  int tid = threadIdx.x;
  int b = blockIdx.x;
  int dir = blockIdx.y;
  const unsigned* staging = dir ? staging_out : staging_in;
  const int* boff = dir ? boff_out : boff_in;
  int* off = dir ? off_out : off_in;
  int* csr = dir ? csr_out : csr_in;
  int ebase = boff[b], eend = boff[b + 1];
  int node_base = b << BSHIFT;
  int nnodes = min(BSIZE, N_NODES - node_base);
  cnt[2 * tid] = 0; cnt[2 * tid + 1] = 0;
  __syncthreads();
  for (int e = ebase + tid; e < eend; e += 256)
    atomicAdd(&cnt[staging[e] >> 18], 1);
  __syncthreads();
  int i0 = 2 * tid, i1 = 2 * tid + 1;
  int a0 = cnt[i0], a1 = cnt[i1];
  int pair = a0 + a1;
  int lane = tid & 63, wid = tid >> 6;
  int incl = pair;
#pragma unroll
  for (int o = 1; o < 64; o <<= 1) { int t = __shfl_up(incl, o); if (lane >= o) incl += t; }
  if (lane == 63) wtot[wid] = incl;
  __syncthreads();
  if (tid == 0) { int r = 0; for (int w = 0; w < 4; w++) { int v = wtot[w]; wtot[w] = r; r += v; } }
  __syncthreads();
  int exclp = incl - pair + wtot[wid];
  cnt[i0] = exclp;
  cnt[i1] = exclp + a0;
  __syncthreads();
  for (int i = tid; i < nnodes; i += 256) off[node_base + i] = ebase + cnt[i];
  if (b == KB - 1 && tid == 0) off[N_NODES] = boff[KB];
  __syncthreads();
  for (int e = ebase + tid; e < eend; e += 256) {
    unsigned rec = staging[e];
    int p = atomicAdd(&cnt[rec >> 18], 1);
    csr[ebase + p] = (int)(rec & PAYMASK);
  }
}

// ---------------------------------------------------------------------------
// Prep: swizzle wh (32x1024 f32) into mfma B-fragment order, bf16.
// ---------------------------------------------------------------------------
__global__ void __launch_bounds__(256) prep_whfrag_kernel(
    const float* __restrict__ wh, unsigned short* __restrict__ wh_frag) {
  int id = blockIdx.x * 256 + threadIdx.x;
  if (id >= 64 * 64 * 8) return;
  int t = id >> 9;
  int rem = id & 511;
  int lane = rem >> 3;
  int i = rem & 7;
  int k = (lane >> 4) * 8 + i;
  int n = t * 16 + (lane & 15);
  wh_frag[id] = (unsigned short)bf16_bits(wh[(size_t)k * HID + n]);
}

// ---------------------------------------------------------------------------
// Pack 32 fp32 acc channels into split bf16 arrays (16 ch each, 32 B rows)
// ---------------------------------------------------------------------------
__device__ __forceinline__ void store_split(unsigned short* y_out,
                                            unsigned short* y_back,
                                            int i, const float* acc) {
  uint4 t0, t1;
  t0.x = pack_bf2(acc[0], acc[1]);   t0.y = pack_bf2(acc[2], acc[3]);
  t0.z = pack_bf2(acc[4], acc[5]);   t0.w = pack_bf2(acc[6], acc[7]);
  t1.x = pack_bf2(acc[8], acc[9]);   t1.y = pack_bf2(acc[10], acc[11]);
  t1.z = pack_bf2(acc[12], acc[13]); t1.w = pack_bf2(acc[14], acc[15]);
  uint4* po = (uint4*)(y_out + (size_t)i * 16);
  po[0] = t0; po[1] = t1;
  t0.x = pack_bf2(acc[16], acc[17]); t0.y = pack_bf2(acc[18], acc[19]);
  t0.z = pack_bf2(acc[20], acc[21]); t0.w = pack_bf2(acc[22], acc[23]);
  t1.x = pack_bf2(acc[24], acc[25]); t1.y = pack_bf2(acc[26], acc[27]);
  t1.z = pack_bf2(acc[28], acc[29]); t1.w = pack_bf2(acc[30], acc[31]);
  uint4* pb = (uint4*)(y_back + (size_t)i * 16);
  pb[0] = t0; pb[1] = t1;
}

// ---------------------------------------------------------------------------
// A0: x0 = emb[nodes]; y = x0 @ [w0_out | w0_back]
// ---------------------------------------------------------------------------
__global__ void __launch_bounds__(256) emb_mm_kernel(
    const int* __restrict__ nodes, const float* __restrict__ emb,
    const float* __restrict__ w_out, const float* __restrict__ w_back,
    unsigned short* __restrict__ y_out, unsigned short* __restrict__ y_back) {
  __shared__ float W[CH][CH];
  __shared__ float Esh[NT * CH];
  int tid = threadIdx.x;
  for (int t = tid; t < CH * CH; t += blockDim.x) {
    int k = t >> 5, j = t & 31;
    W[k][j] = (j < 16) ? w_out[k * 16 + j] : w_back[k * 16 + j - 16];
  }
  for (int t = tid; t < NT * CH; t += blockDim.x) Esh[t] = emb[t];
  __syncthreads();
  int i = blockIdx.x * blockDim.x + tid;
  if (i >= N_NODES) return;
  int tn = nodes[i];
  float v[CH];
#pragma unroll
  for (int k = 0; k < CH; k++) v[k] = Esh[tn * CH + k];
  float acc[CH];
#pragma unroll
  for (int j = 0; j < CH; j++) acc[j] = 0.f;
#pragma unroll
  for (int k = 0; k < CH; k++) {
    float vk = v[k];
#pragma unroll
    for (int j = 0; j < CH; j++) acc[j] += vk * W[k][j];
  }
  store_split(y_out, y_back, i, acc);
}

// ---------------------------------------------------------------------------
// A: y = relu(bn(x)) @ [w_out | w_back]
// ---------------------------------------------------------------------------
__global__ void __launch_bounds__(256) bn_relu_mm_kernel(
    const float* __restrict__ xin, const float* __restrict__ stats,
    const float* __restrict__ gamma, const float* __restrict__ beta,
    const float* __restrict__ w_out, const float* __restrict__ w_back,
    unsigned short* __restrict__ y_out, unsigned short* __restrict__ y_back) {
  __shared__ float W[CH][CH];
  __shared__ float sc[CH], sh[CH];
  int tid = threadIdx.x;
  for (int t = tid; t < CH * CH; t += blockDim.x) {
    int k = t >> 5, j = t & 31;
    W[k][j] = (j < 16) ? w_out[k * 16 + j] : w_back[k * 16 + j - 16];
  }
  if (tid < CH) {
    float m  = stats[tid] * (1.0f / N_NODES);
    float s2 = stats[CH + tid] * (1.0f / N_NODES);
    float var = s2 - m * m;
    float scale = gamma[tid] * rsqrtf(var + BN_EPS);
    sc[tid] = scale;
    sh[tid] = beta[tid] - m * scale;
  }
  __syncthreads();
  int i = blockIdx.x * blockDim.x + tid;
  if (i >= N_NODES) return;
  const float4* xp = (const float4*)(xin + (size_t)i * CH);
  float v[CH];
#pragma unroll
  for (int q = 0; q < 8; q++) {
    float4 t = xp[q];
    v[4 * q + 0] = fmaxf(t.x * sc[4 * q + 0] + sh[4 * q + 0], 0.f);
    v[4 * q + 1] = fmaxf(t.y * sc[4 * q + 1] + sh[4 * q + 1], 0.f);
    v[4 * q + 2] = fmaxf(t.z * sc[4 * q + 2] + sh[4 * q + 2], 0.f);
    v[4 * q + 3] = fmaxf(t.w * sc[4 * q + 3] + sh[4 * q + 3], 0.f);
  }
  float acc[CH];
#pragma unroll
  for (int j = 0; j < CH; j++) acc[j] = 0.f;
#pragma unroll
  for (int k = 0; k < CH; k++) {
    float vk = v[k];
#pragma unroll
    for (int j = 0; j < CH; j++) acc[j] += vk * W[k][j];
  }
  store_split(y_out, y_back, i, acc);
}

// ---------------------------------------------------------------------------
// B: node-parallel gather aggregation (R9 structure, measured best)
// ---------------------------------------------------------------------------
__global__ void __launch_bounds__(256) agg_dir_kernel(
    const unsigned short* __restrict__ y_out, const unsigned short* __restrict__ y_back,
    const float* __restrict__ xres, float* __restrict__ out,
    const int* __restrict__ off_in, const int* __restrict__ csr_in,
    const int* __restrict__ off_out, const int* __restrict__ csr_out,
    float* __restrict__ stats) {
  __shared__ float ssum[CH], sssq[CH];
  int tid = threadIdx.x;
  if (tid < CH) { ssum[tid] = 0.f; sssq[tid] = 0.f; }
  __syncthreads();
  int dir = blockIdx.y;
  const unsigned short* y = dir ? y_back : y_out;
  const int* off = dir ? off_out : off_in;
  const int* csr = dir ? csr_out : csr_in;
  int chanbase = dir * 16;
  int t = blockIdx.x * 256 + tid;
  bool valid = t < 2 * N_NODES;
  int q = t & 1;
  int i = valid ? (t >> 1) : 0;
  int lo = 0, hi = 0;
  if (valid) { lo = off[i]; hi = off[i + 1]; }
  int q8 = q * 8;
  float a0 = 0.f, a1 = 0.f, a2 = 0.f, a3 = 0.f;
  float a4 = 0.f, a5 = 0.f, a6 = 0.f, a7 = 0.f;
  int e = lo;
  for (; e + 8 <= hi; e += 8) {
    int n0 = csr[e + 0], n1 = csr[e + 1], n2 = csr[e + 2], n3 = csr[e + 3];
    int n4 = csr[e + 4], n5 = csr[e + 5], n6 = csr[e + 6], n7 = csr[e + 7];
    uint4 p0 = *(const uint4*)(y + (size_t)n0 * 16 + q8);
    uint4 p1 = *(const uint4*)(y + (size_t)n1 * 16 + q8);
    uint4 p2 = *(const uint4*)(y + (size_t)n2 * 16 + q8);
    uint4 p3 = *(const uint4*)(y + (size_t)n3 * 16 + q8);
    uint4 p4 = *(const uint4*)(y + (size_t)n4 * 16 + q8);
    uint4 p5 = *(const uint4*)(y + (size_t)n5 * 16 + q8);
    uint4 p6 = *(const uint4*)(y + (size_t)n6 * 16 + q8);
    uint4 p7 = *(const uint4*)(y + (size_t)n7 * 16 + q8);
    a0 += BF_LO(p0.x) + BF_LO(p1.x) + BF_LO(p2.x) + BF_LO(p3.x)
        + BF_LO(p4.x) + BF_LO(p5.x) + BF_LO(p6.x) + BF_LO(p7.x);
    a1 += BF_HI(p0.x) + BF_HI(p1.x) + BF_HI(p2.x) + BF_HI(p3.x)
        + BF_HI(p4.x) + BF_HI(p5.x) + BF_HI(p6.x) + BF_HI(p7.x);
    a2 += BF_LO(p0.y) + BF_LO(p1.y) + BF_LO(p2.y) + BF_LO(p3.y)
        + BF_LO(p4.y) + BF_LO(p5.y) + BF_LO(p6.y) + BF_LO(p7.y);
    a3 += BF_HI(p0.y) + BF_HI(p1.y) + BF_HI(p2.y) + BF_HI(p3.y)
        + BF_HI(p4.y) + BF_HI(p5.y) + BF_HI(p6.y) + BF_HI(p7.y);
    a4 += BF_LO(p0.z) + BF_LO(p1.z) + BF_LO(p2.z) + BF_LO(p3.z)
        + BF_LO(p4.z) + BF_LO(p5.z) + BF_LO(p6.z) + BF_LO(p7.z);
    a5 += BF_HI(p0.z) + BF_HI(p1.z) + BF_HI(p2.z) + BF_HI(p3.z)
        + BF_HI(p4.z) + BF_HI(p5.z) + BF_HI(p6.z) + BF_HI(p7.z);
    a6 += BF_LO(p0.w) + BF_LO(p1.w) + BF_LO(p2.w) + BF_LO(p3.w)
        + BF_LO(p4.w) + BF_LO(p5.w) + BF_LO(p6.w) + BF_LO(p7.w);
    a7 += BF_HI(p0.w) + BF_HI(p1.w) + BF_HI(p2.w) + BF_HI(p3.w)
        + BF_HI(p4.w) + BF_HI(p5.w) + BF_HI(p6.w) + BF_HI(p7.w);
  }
  for (; e + 4 <= hi; e += 4) {
    int n0 = csr[e + 0], n1 = csr[e + 1], n2 = csr[e + 2], n3 = csr[e + 3];
    uint4 p0 = *(const uint4*)(y + (size_t)n0 * 16 + q8);
    uint4 p1 = *(const uint4*)(y + (size_t)n1 * 16 + q8);
    uint4 p2 = *(const uint4*)(y + (size_t)n2 * 16 + q8);
    uint4 p3 = *(const uint4*)(y + (size_t)n3 * 16 + q8);
    a0 += BF_LO(p0.x) + BF_LO(p1.x) + BF_LO(p2.x) + BF_LO(p3.x);
    a1 += BF_HI(p0.x) + BF_HI(p1.x) + BF_HI(p2.x) + BF_HI(p3.x);
    a2 += BF_LO(p0.y) + BF_LO(p1.y) + BF_LO(p2.y) + BF_LO(p3.y);
    a3 += BF_HI(p0.y) + BF_HI(p1.y) + BF_HI(p2.y) + BF_HI(p3.y);
    a4 += BF_LO(p0.z) + BF_LO(p1.z) + BF_LO(p2.z) + BF_LO(p3.z);
    a5 += BF_HI(p0.z) + BF_HI(p1.z) + BF_HI(p2.z) + BF_HI(p3.z);
    a6 += BF_LO(p0.w) + BF_LO(p1.w) + BF_LO(p2.w) + BF_LO(p3.w);
    a7 += BF_HI(p0.w) + BF_HI(p1.w) + BF_HI(p2.w) + BF_HI(p3.w);
  }
  for (; e < hi; e++) {
    int nb = csr[e];
    uint4 p = *(const uint4*)(y + (size_t)nb * 16 + q8);
    a0 += BF_LO(p.x); a1 += BF_HI(p.x);
    a2 += BF_LO(p.y); a3 += BF_HI(p.y);
    a4 += BF_LO(p.z); a5 += BF_HI(p.z);
    a6 += BF_LO(p.w); a7 += BF_HI(p.w);
  }
  if (valid && xres) {
    const float4* rp = (const float4*)(xres + (size_t)i * CH + chanbase + q8);
    float4 r0 = rp[0], r1 = rp[1];
    a0 += r0.x; a1 += r0.y; a2 += r0.z; a3 += r0.w;
    a4 += r1.x; a5 += r1.y; a6 += r1.z; a7 += r1.w;
  }
  if (valid) {
    float4* op = (float4*)(out + (size_t)i * CH + chanbase + q8);
    op[0] = make_float4(a0, a1, a2, a3);
    op[1] = make_float4(a4, a5, a6, a7);
  }
  if (stats) {
    float s0 = a0 * a0, s1 = a1 * a1, s2 = a2 * a2, s3 = a3 * a3;
    float s4 = a4 * a4, s5 = a5 * a5, s6 = a6 * a6, s7 = a7 * a7;
#pragma unroll
    for (int o = 32; o >= 2; o >>= 1) {
      a0 += __shfl_down(a0, o); a1 += __shfl_down(a1, o);
      a2 += __shfl_down(a2, o); a3 += __shfl_down(a3, o);
      a4 += __shfl_down(a4, o); a5 += __shfl_down(a5, o);
      a6 += __shfl_down(a6, o); a7 += __shfl_down(a7, o);
      s0 += __shfl_down(s0, o); s1 += __shfl_down(s1, o);
      s2 += __shfl_down(s2, o); s3 += __shfl_down(s3, o);
      s4 += __shfl_down(s4, o); s5 += __shfl_down(s5, o);
      s6 += __shfl_down(s6, o); s7 += __shfl_down(s7, o);
    }
    if ((tid & 63) < 2) {
      int cb = chanbase + q8;
      atomicAdd(&ssum[cb + 0], a0); atomicAdd(&ssum[cb + 1], a1);
      atomicAdd(&ssum[cb + 2], a2); atomicAdd(&ssum[cb + 3], a3);
      atomicAdd(&ssum[cb + 4], a4); atomicAdd(&ssum[cb + 5], a5);
      atomicAdd(&ssum[cb + 6], a6); atomicAdd(&ssum[cb + 7], a7);
      atomicAdd(&sssq[cb + 0], s0); atomicAdd(&sssq[cb + 1], s1);
      atomicAdd(&sssq[cb + 2], s2); atomicAdd(&sssq[cb + 3], s3);
      atomicAdd(&sssq[cb + 4], s4); atomicAdd(&sssq[cb + 5], s5);
      atomicAdd(&sssq[cb + 6], s6); atomicAdd(&sssq[cb + 7], s7);
    }
    __syncthreads();
    if (tid < 16) {
      int c = chanbase + tid;
      atomicAdd(&stats[c], ssum[c]);
      atomicAdd(&stats[CH + c], sssq[c]);
    }
  }
}

// ---------------------------------------------------------------------------
// MLP head via MFMA (R11, measured win)
// ---------------------------------------------------------------------------
__global__ void __launch_bounds__(256) score_mfma_kernel(
    const float* __restrict__ x, const int* __restrict__ indices,
    const int* __restrict__ assignment,
    const unsigned short* __restrict__ wh_frag, const float* __restrict__ bh,
    const float* __restrict__ wo,
    float* __restrict__ s, int* __restrict__ seg) {
  __shared__ __align__(16) unsigned short a_lds[64 * 32];
  __shared__ float bh_lds[HID];
  __shared__ float wo_lds[HID];
  int tid = threadIdx.x;
  int m0 = blockIdx.x * 64;
#pragma unroll
  for (int u = 0; u < 4; u++) {
    bh_lds[u * 256 + tid] = bh[u * 256 + tid];
    wo_lds[u * 256 + tid] = wo[u * 256 + tid];
  }
  {
    int r = tid >> 2, part = tid & 3;
    int m = m0 + r;
    unsigned short* dstp = &a_lds[r * 32 + part * 8];
    if (m < M_SEL) {
      int idx = indices[m];
      const float4* xp = (const float4*)(x + (size_t)idx * CH + part * 8);
      float4 v0 = xp[0], v1 = xp[1];
      uint4 packed;
      packed.x = pack_bf2(fmaxf(v0.x, 0.f), fmaxf(v0.y, 0.f));
      packed.y = pack_bf2(fmaxf(v0.z, 0.f), fmaxf(v0.w, 0.f));
      packed.z = pack_bf2(fmaxf(v1.x, 0.f), fmaxf(v1.y, 0.f));
      packed.w = pack_bf2(fmaxf(v1.z, 0.f), fmaxf(v1.w, 0.f));
      *(uint4*)dstp = packed;
      if (part == 0) seg[m] = assignment[idx];
    } else {
      *(uint4*)dstp = make_uint4(0, 0, 0, 0);
    }
  }
  __syncthreads();
  int w = tid >> 6;
  int lane = tid & 63;
  int quad = lane >> 4;
  int col = lane & 15;
  bf16x8 afrag = *(const bf16x8*)&a_lds[(w * 16 + col) * 32 + quad * 8];
  float racc0 = 0.f, racc1 = 0.f, racc2 = 0.f, racc3 = 0.f;
  for (int t = 0; t < 64; t++) {
    bf16x8 bfrag = *(const bf16x8*)&wh_frag[(size_t)(t * 64 + lane) * 8];
    f32x4 c = __builtin_amdgcn_mfma_f32_16x16x32_bf16(afrag, bfrag,
                                                      (f32x4){0.f, 0.f, 0.f, 0.f},
                                                      0, 0, 0);
    int n = t * 16 + col;
    float bhv = bh_lds[n], wov = wo_lds[n];
    racc0 += fmaxf(c[0] + bhv, 0.f) * wov;
    racc1 += fmaxf(c[1] + bhv, 0.f) * wov;
    racc2 += fmaxf(c[2] + bhv, 0.f) * wov;
    racc3 += fmaxf(c[3] + bhv, 0.f) * wov;
  }
#pragma unroll
  for (int o = 8; o >= 1; o >>= 1) {
    racc0 += __shfl_xor(racc0, o);
    racc1 += __shfl_xor(racc1, o);
    racc2 += __shfl_xor(racc2, o);
    racc3 += __shfl_xor(racc3, o);
  }
  if (col == 0) {
    int mrow = m0 + w * 16 + quad * 4;
    if (mrow + 0 < M_SEL) s[mrow + 0] = racc0;
    if (mrow + 1 < M_SEL) s[mrow + 1] = racc1;
    if (mrow + 2 < M_SEL) s[mrow + 2] = racc2;
    if (mrow + 3 < M_SEL) s[mrow + 3] = racc3;
  }
}

// ---------------------------------------------------------------------------
// Segmented log-softmax
// ---------------------------------------------------------------------------
__device__ __forceinline__ int lower_bound_dev(const int* a, int n, int key) {
  int lo = 0, hi = n;
  while (lo < hi) { int mid = (lo + hi) >> 1; if (a[mid] < key) lo = mid + 1; else hi = mid; }
  return lo;
}

__global__ void __launch_bounds__(256) logsoftmax_kernel(
    const float* __restrict__ s, const int* __restrict__ seg, float* __restrict__ out) {
  __shared__ float red[256];
  __shared__ int bounds[2];
  int tid = threadIdx.x;
  int b = blockIdx.x;
  if (tid == 0) {
    bounds[0] = lower_bound_dev(seg, M_SEL, b);
    bounds[1] = lower_bound_dev(seg, M_SEL, b + 1);
  }
  __syncthreads();
  int lo = bounds[0], hi = bounds[1];
  float mx = -INFINITY;
  for (int i = lo + tid; i < hi; i += 256) mx = fmaxf(mx, s[i]);
  red[tid] = mx; __syncthreads();
  for (int o = 128; o > 0; o >>= 1) { if (tid < o) red[tid] = fmaxf(red[tid], red[tid + o]); __syncthreads(); }
  float mxv = red[0];
  __syncthreads();
  float sum = 0.f;
  for (int i = lo + tid; i < hi; i += 256) sum += expf(s[i] - mxv);
  red[tid] = sum; __syncthreads();
  for (int o = 128; o > 0; o >>= 1) { if (tid < o) red[tid] += red[tid + o]; __syncthreads(); }
  float lse = logf(red[0]);
  for (int i = lo + tid; i < hi; i += 256) out[i] = (s[i] - mxv) - lse;
}

// ---------------------------------------------------------------------------
extern "C" void kernel_launch(void* const* d_in, const int* in_sizes, int n_in,
                              void* d_out, int out_size, void* d_ws, size_t ws_size,
                              hipStream_t stream) {
  const int*   assignment = (const int*)d_in[1];
  const int*   nodes      = (const int*)d_in[2];
  const int*   src        = (const int*)d_in[3];
  const int*   dst        = (const int*)d_in[4];
  const int*   indices    = (const int*)d_in[5];
  const float* emb        = (const float*)d_in[6];
  const float* w0_out     = (const float*)d_in[7];
  const float* w0_back    = (const float*)d_in[8];
  const float* bn1_gamma  = (const float*)d_in[9];
  const float* bn1_beta   = (const float*)d_in[10];
  const float* w1_out     = (const float*)d_in[11];
  const float* w1_back    = (const float*)d_in[12];
  const float* bn2_gamma  = (const float*)d_in[13];
  const float* bn2_beta   = (const float*)d_in[14];
  const float* w2_out     = (const float*)d_in[15];
  const float* w2_back    = (const float*)d_in[16];
  const float* wh         = (const float*)d_in[17];
  const float* bh         = (const float*)d_in[18];
  const float* wo         = (const float*)d_in[19];
  float* out = (float*)d_out;

  char* ws = (char*)d_ws;
  size_t off = 0;
  auto alloc = [&](size_t bytes) {
    char* p = ws + off;
    off = (off + bytes + 255) & ~(size_t)255;
    return p;
  };
  // bcnt_in/bcnt_out contiguous in ONE alloc (single memset must cover both)
  int* bcnt_in  = (int*)alloc((size_t)2 * KB * 4); int* bcnt_out = bcnt_in + KB;
  int* boff_in  = (int*)alloc((size_t)(KB + 1) * 4);
  int* boff_out = (int*)alloc((size_t)(KB + 1) * 4);
  int* gcur_in  = (int*)alloc((size_t)KB * 4);
  int* gcur_out = (int*)alloc((size_t)KB * 4);
  int* off_in   = (int*)alloc((size_t)(N_NODES + 1) * 4);
  int* off_out  = (int*)alloc((size_t)(N_NODES + 1) * 4);
  float* stats  = (float*)alloc((size_t)16 * 64 * 4);
  int* csr_in   = (int*)alloc((size_t)N_EDGES * 4);
  int* csr_out  = (int*)alloc((size_t)N_EDGES * 4);
  unsigned short* wh_frag = (unsigned short*)alloc((size_t)64 * 64 * 8 * 2);
  unsigned short* y_out  = (unsigned short*)alloc((size_t)N_NODES * 16 * 2);
  unsigned short* y_back = (unsigned short*)alloc((size_t)N_NODES * 16 * 2);
  float* xb = (float*)alloc((size_t)N_NODES * CH * 4);
  float* hb = (float*)alloc((size_t)N_NODES * CH * 4);
  float* sb = (float*)alloc((size_t)M_SEL * 4);
  int* segb = (int*)alloc((size_t)M_SEL * 4);
  // staging aliases xb (consumed by build_kernel before xb is first written)
  unsigned* staging_in  = (unsigned*)xb;
  unsigned* staging_out = (unsigned*)xb + N_EDGES;

  hipMemsetAsync(bcnt_in, 0, (size_t)2 * KB * 4, stream);
  hipMemsetAsync(stats, 0, (size_t)16 * 64 * 4, stream);

  bin_count_kernel<<<1024, 256, 0, stream>>>(src, dst, bcnt_in, bcnt_out);
  bucket_scan_kernel<<<1, 256, 0, stream>>>(bcnt_in, boff_in, gcur_in,
                                            bcnt_out, boff_out, gcur_out);
  dim3 gStage((N_EDGES + STAGE_BATCH - 1) / STAGE_BATCH, 2);  // (196, 2)
  stage_kernel<<<gStage, 256, 0, stream>>>(src, dst, gcur_in, staging_in,
                                           gcur_out, staging_out);
  dim3 gBuild(KB, 2);
  build_kernel<<<gBuild, 256, 0, stream>>>(staging_in, boff_in, off_in, csr_in,
                                           staging_out, boff_out, off_out, csr_out);
  prep_whfrag_kernel<<<(64 * 64 * 8 + 255) / 256, 256, 0, stream>>>(wh, wh_frag);

  const int gA = (N_NODES + 255) / 256;
  dim3 gAgg((2 * N_NODES + 255) / 256, 2);  // (1563, 2), tail-guarded
  auto agg_pass = [&](const float* xres, float* outb, float* st) {
    agg_dir_kernel<<<gAgg, 256, 0, stream>>>(y_out, y_back, xres, outb,
                                             off_in, csr_in, off_out, csr_out, st);
  };

  emb_mm_kernel<<<gA, 256, 0, stream>>>(nodes, emb, w0_out, w0_back, y_out, y_back);
  agg_pass(nullptr, xb, stats + 0 * 64);
  for (int l = 0; l < NL; l++) {
    bn_relu_mm_kernel<<<gA, 256, 0, stream>>>(xb, stats + (2 * l) * 64,
                                              bn1_gamma + l * CH, bn1_beta + l * CH,
                                              w1_out + l * CH * 16, w1_back + l * CH * 16,
                                              y_out, y_back);
    agg_pass(nullptr, hb, stats + (2 * l + 1) * 64);
    bn_relu_mm_kernel<<<gA, 256, 0, stream>>>(hb, stats + (2 * l + 1) * 64,
                                              bn2_gamma + l * CH, bn2_beta + l * CH,
                                              w2_out + l * CH * 16, w2_back + l * CH * 16,
                                              y_out, y_back);
    agg_pass(xb, xb, (l < NL - 1) ? (stats + (2 * l + 2) * 64) : nullptr);
  }
  score_mfma_kernel<<<(M_SEL + 63) / 64, 256, 0, stream>>>(
      xb, indices, assignment, wh_frag, bh, wo, sb, segb);
  logsoftmax_kernel<<<NEX, 256, 0, stream>>>(sb, segb, out);
}